// Round 1
// baseline (1052.820 us; speedup 1.0000x reference)
//
#include <hip/hip_runtime.h>

// ---------------------------------------------------------------------------
// 2-layer GCN forward on MI355X.
// deg/dinv -> GEMM1 (f32 tiled) -> self+bias init -> edge scatter (atomics)
// -> GEMM2 (relu folded into A-load) -> self+bias init -> edge scatter.
// ---------------------------------------------------------------------------

__global__ void init_deg_kernel(float* __restrict__ deg, int n) {
    int i = blockIdx.x * blockDim.x + threadIdx.x;
    if (i < n) deg[i] = 1.0f;  // self-loop
}

__global__ void count_deg_kernel(const int* __restrict__ dst, float* __restrict__ deg, int e) {
    int i = blockIdx.x * blockDim.x + threadIdx.x;
    if (i < e) atomicAdd(&deg[dst[i]], 1.0f);
}

__global__ void make_dinv_kernel(const float* __restrict__ deg, float* __restrict__ dinv, int n) {
    int i = blockIdx.x * blockDim.x + threadIdx.x;
    if (i < n) dinv[i] = rsqrtf(deg[i]);
}

// out[v][c] = bias[c] + dinv[v]^2 * h[v][c]   (also serves as the zero-init
// for the following atomic scatter; d_out/d_ws arrive poisoned 0xAA)
__global__ void self_init_kernel(const float* __restrict__ h, const float* __restrict__ dinv,
                                 const float* __restrict__ bias, float* __restrict__ out,
                                 int total, int shift) {
    int idx = blockIdx.x * blockDim.x + threadIdx.x;
    if (idx >= total) return;
    int v = idx >> shift;
    int c = idx & ((1 << shift) - 1);
    float di = dinv[v];
    out[idx] = bias[c] + di * di * h[idx];
}

// One wave per edge, 128 channels: lane handles 2 floats (float2 gather, 512B/row)
__global__ void scatter128_kernel(const int* __restrict__ src, const int* __restrict__ dst,
                                  const float* __restrict__ dinv, const float* __restrict__ h,
                                  float* __restrict__ out, int e) {
    int eIdx = blockIdx.x * 4 + (threadIdx.x >> 6);
    if (eIdx >= e) return;
    int lane = threadIdx.x & 63;
    int s = src[eIdx], d = dst[eIdx];
    float w = dinv[s] * dinv[d];
    float2 v = *((const float2*)(h + (size_t)s * 128) + lane);
    float* orow = out + (size_t)d * 128 + lane * 2;
    atomicAdd(orow,     v.x * w);
    atomicAdd(orow + 1, v.y * w);
}

// One wave per edge, 64 channels: lane == channel
__global__ void scatter64_kernel(const int* __restrict__ src, const int* __restrict__ dst,
                                 const float* __restrict__ dinv, const float* __restrict__ h,
                                 float* __restrict__ out, int e) {
    int eIdx = blockIdx.x * 4 + (threadIdx.x >> 6);
    if (eIdx >= e) return;
    int lane = threadIdx.x & 63;
    int s = src[eIdx], d = dst[eIdx];
    float w = dinv[s] * dinv[d];
    float v = h[(size_t)s * 64 + lane];
    atomicAdd(out + (size_t)d * 64 + lane, v * w);
}

// ---------------------------------------------------------------------------
// Tiled f32 GEMM: C[M,N] = op(A)[M,K] @ B[K,N].  256 threads, BMxBN tile,
// register tile TM x TN.  RELU applies relu to A elements on load (layer-2
// input activation).  Requires: N == BN*gridDim.y? no — single column tile:
// BN == N.  K % BK == 0.  TM == 4.
// ---------------------------------------------------------------------------
template <int BM, int BN, int BK, int TM, int TN, bool RELU>
__global__ __launch_bounds__(256) void gemm_kernel(const float* __restrict__ A,
                                                   const float* __restrict__ B,
                                                   float* __restrict__ C,
                                                   int M, int N, int K) {
    static_assert(TM == 4, "A fragment read assumes TM==4");
    static_assert((BM / TM) * (BN / TN) == 256, "need 256 threads");
    __shared__ float As[BK][BM];   // transposed A tile (k-major)
    __shared__ float Bs[BK][BN];

    const int tid = threadIdx.x;
    constexpr int CG = BN / TN;            // column groups
    const int tx = tid % CG;
    const int ty = tid / CG;
    const int rowBase = blockIdx.x * BM;

    float acc[TM][TN];
#pragma unroll
    for (int i = 0; i < TM; i++)
#pragma unroll
        for (int j = 0; j < TN; j++) acc[i][j] = 0.0f;

    // A staging: BM*BK/256 = 4 floats/thread = one float4 along K
    static_assert(BM * BK == 1024, "A staging mapping assumes BM*BK==1024");
    const int aRow = tid / (BK / 4);
    const int aK4  = tid % (BK / 4);
    int arow_g = rowBase + aRow;
    if (arow_g >= M) arow_g = M - 1;       // clamp (harmless re-read, stores guarded)
    const float* Aptr = A + (size_t)arow_g * K + aK4 * 4;

    constexpr int BF4 = (BK * BN) / 1024;  // float4 per thread for B staging

    for (int k0 = 0; k0 < K; k0 += BK) {
        float4 av4 = *(const float4*)(Aptr + k0);
        if (RELU) {
            av4.x = fmaxf(av4.x, 0.0f); av4.y = fmaxf(av4.y, 0.0f);
            av4.z = fmaxf(av4.z, 0.0f); av4.w = fmaxf(av4.w, 0.0f);
        }
        As[aK4 * 4 + 0][aRow] = av4.x;
        As[aK4 * 4 + 1][aRow] = av4.y;
        As[aK4 * 4 + 2][aRow] = av4.z;
        As[aK4 * 4 + 3][aRow] = av4.w;
#pragma unroll
        for (int i = 0; i < BF4; i++) {
            int f4 = tid + i * 256;
            int br = f4 / (BN / 4);
            int bc = (f4 % (BN / 4)) * 4;
            *(float4*)&Bs[br][bc] = *(const float4*)(B + (size_t)(k0 + br) * N + bc);
        }
        __syncthreads();
#pragma unroll
        for (int k = 0; k < BK; k++) {
            float a[TM], b[TN];
            *(float4*)a = *(const float4*)&As[k][ty * TM];
#pragma unroll
            for (int j = 0; j < TN / 4; j++)
                *(float4*)(b + 4 * j) = *(const float4*)&Bs[k][tx * TN + 4 * j];
#pragma unroll
            for (int i = 0; i < TM; i++)
#pragma unroll
                for (int j = 0; j < TN; j++)
                    acc[i][j] = fmaf(a[i], b[j], acc[i][j]);
        }
        __syncthreads();
    }

#pragma unroll
    for (int i = 0; i < TM; i++) {
        int r = rowBase + ty * TM + i;
        if (r < M) {
#pragma unroll
            for (int j = 0; j < TN / 4; j++) {
                float4 o = make_float4(acc[i][4 * j + 0], acc[i][4 * j + 1],
                                       acc[i][4 * j + 2], acc[i][4 * j + 3]);
                *(float4*)(C + (size_t)r * N + tx * TN + 4 * j) = o;
            }
        }
    }
}

extern "C" void kernel_launch(void* const* d_in, const int* in_sizes, int n_in,
                              void* d_out, int out_size, void* d_ws, size_t ws_size,
                              hipStream_t stream) {
    const float* x  = (const float*)d_in[0];
    const int*   ei = (const int*)d_in[1];   // [2, E] flat: src then dst
    const float* W1 = (const float*)d_in[2];
    const float* b1 = (const float*)d_in[3];
    const float* W2 = (const float*)d_in[4];
    const float* b2 = (const float*)d_in[5];
    float* out = (float*)d_out;

    const int IN_C = 256, HID_C = 128, OUT_C = 64;
    const int N = in_sizes[0] / IN_C;
    const int E = in_sizes[1] / 2;
    const int* srcA = ei;
    const int* dstA = ei + E;

    char* ws = (char*)d_ws;
    float* deg  = (float*)(ws);
    float* dinv = (float*)(ws + (size_t)256 * 1024);
    float* h1   = (float*)(ws + (size_t)512 * 1024);                        // N*128
    float* a1   = (float*)(ws + (size_t)512 * 1024 + 26ull * 1024 * 1024);  // N*128
    float* h2   = h1;  // h1 dead after scatter1; reuse for N*64

    const int nb256 = (N + 255) / 256;

    // degree + norm
    init_deg_kernel<<<nb256, 256, 0, stream>>>(deg, N);
    count_deg_kernel<<<(E + 255) / 256, 256, 0, stream>>>(dstA, deg, E);
    make_dinv_kernel<<<nb256, 256, 0, stream>>>(deg, dinv, N);

    // layer 1: h1 = x @ W1
    gemm_kernel<64, 128, 16, 4, 8, false>
        <<<(N + 63) / 64, 256, 0, stream>>>(x, W1, h1, N, HID_C, IN_C);
    // a1[v] = b1 + dinv[v]^2 * h1[v]
    self_init_kernel<<<(N * HID_C + 255) / 256, 256, 0, stream>>>(
        h1, dinv, b1, a1, N * HID_C, 7);
    // a1[dst] += dinv[src]*dinv[dst]*h1[src]
    scatter128_kernel<<<(E + 3) / 4, 256, 0, stream>>>(srcA, dstA, dinv, h1, a1, E);

    // layer 2: h2 = relu(a1) @ W2
    gemm_kernel<64, 64, 16, 4, 4, true>
        <<<(N + 63) / 64, 256, 0, stream>>>(a1, W2, h2, N, OUT_C, HID_C);
    // out[v] = b2 + dinv[v]^2 * h2[v]
    self_init_kernel<<<(N * OUT_C + 255) / 256, 256, 0, stream>>>(
        h2, dinv, b2, out, N * OUT_C, 6);
    // out[dst] += dinv[src]*dinv[dst]*h2[src]
    scatter64_kernel<<<(E + 3) / 4, 256, 0, stream>>>(srcA, dstA, dinv, h2, out, E);
}

// Round 2
// 494.635 us; speedup vs baseline: 2.1285x; 2.1285x over previous
//
#include <hip/hip_runtime.h>

// ---------------------------------------------------------------------------
// 2-layer GCN forward on MI355X — round 2.
// R1 post-mortem: float atomic scatters were 985/1053 µs. Replace with a
// per-launch CSR build (int atomics only) + gather-style aggregation (one
// wave per dst node, register accumulation, single coalesced row write).
// ---------------------------------------------------------------------------

__global__ void zero_int_kernel(int* __restrict__ p, int n) {
    int i = blockIdx.x * blockDim.x + threadIdx.x;
    if (i < n) p[i] = 0;
}

__global__ void copy_int_kernel(const int* __restrict__ a, int* __restrict__ b, int n) {
    int i = blockIdx.x * blockDim.x + threadIdx.x;
    if (i < n) b[i] = a[i];
}

__global__ void count_deg_kernel(const int* __restrict__ dst, int* __restrict__ counts, int e) {
    int i = blockIdx.x * blockDim.x + threadIdx.x;
    if (i < e) atomicAdd(&counts[dst[i]], 1);
}

// dinv[v] = rsqrt(indeg + 1 self-loop)
__global__ void make_dinv_kernel(const int* __restrict__ counts, float* __restrict__ dinv, int n) {
    int i = blockIdx.x * blockDim.x + threadIdx.x;
    if (i < n) dinv[i] = rsqrtf((float)counts[i] + 1.0f);
}

// Single-workgroup exclusive scan over counts[0..n) -> rowptr[0..n], rowptr[n]=total.
__global__ __launch_bounds__(256) void scan_kernel(const int* __restrict__ counts,
                                                   int* __restrict__ rowptr, int n) {
    __shared__ int wsum[4];
    __shared__ int carry_s;
    const int tid = threadIdx.x;
    const int lane = tid & 63, wv = tid >> 6;
    if (tid == 0) carry_s = 0;
    __syncthreads();
    for (int base = 0; base < n; base += 256) {
        int i = base + tid;
        int v = (i < n) ? counts[i] : 0;
        int x = v;
#pragma unroll
        for (int off = 1; off < 64; off <<= 1) {
            int y = __shfl_up(x, off, 64);
            if (lane >= off) x += y;
        }
        if (lane == 63) wsum[wv] = x;
        __syncthreads();
        int wpre = 0;
        for (int k = 0; k < wv; k++) wpre += wsum[k];
        int carry = carry_s;
        if (i < n) rowptr[i] = carry + wpre + (x - v);
        int btot = wsum[0] + wsum[1] + wsum[2] + wsum[3];
        __syncthreads();
        if (tid == 0) carry_s = carry + btot;
    }
    if (tid == 0) rowptr[n] = carry_s;
}

// Scatter edges into CSR order; precompute edge weight dinv[src]*dinv[dst].
__global__ void fill_kernel(const int* __restrict__ src, const int* __restrict__ dst,
                            const float* __restrict__ dinv, int* __restrict__ cursor,
                            int* __restrict__ ssrc, float* __restrict__ swgt, int e) {
    int i = blockIdx.x * blockDim.x + threadIdx.x;
    if (i >= e) return;
    int s = src[i], d = dst[i];
    int pos = atomicAdd(&cursor[d], 1);
    ssrc[pos] = s;
    swgt[pos] = dinv[s] * dinv[d];
}

// One wave per node, 128 channels (float2/lane): out = bias + dinv^2*h_self + sum w*h_src
__global__ __launch_bounds__(256) void agg128_kernel(
    const int* __restrict__ rowptr, const int* __restrict__ ssrc,
    const float* __restrict__ swgt, const float* __restrict__ h,
    const float* __restrict__ dinv, const float* __restrict__ bias,
    float* __restrict__ out, int n) {
    int node = blockIdx.x * 4 + (threadIdx.x >> 6);
    if (node >= n) return;
    int lane = threadIdx.x & 63;
    float di = dinv[node];
    float2 self = *((const float2*)(h + (size_t)node * 128) + lane);
    float accx = di * di * self.x;
    float accy = di * di * self.y;
    int beg = rowptr[node], end = rowptr[node + 1];
#pragma unroll 2
    for (int i = beg; i < end; ++i) {
        int s = ssrc[i];
        float w = swgt[i];
        float2 v = *((const float2*)(h + (size_t)s * 128) + lane);
        accx = fmaf(w, v.x, accx);
        accy = fmaf(w, v.y, accy);
    }
    float2 bv = *((const float2*)bias + lane);
    float2 o = make_float2(accx + bv.x, accy + bv.y);
    *((float2*)(out + (size_t)node * 128) + lane) = o;
}

// One wave per node, 64 channels (lane == channel)
__global__ __launch_bounds__(256) void agg64_kernel(
    const int* __restrict__ rowptr, const int* __restrict__ ssrc,
    const float* __restrict__ swgt, const float* __restrict__ h,
    const float* __restrict__ dinv, const float* __restrict__ bias,
    float* __restrict__ out, int n) {
    int node = blockIdx.x * 4 + (threadIdx.x >> 6);
    if (node >= n) return;
    int lane = threadIdx.x & 63;
    float di = dinv[node];
    float acc = di * di * h[(size_t)node * 64 + lane];
    int beg = rowptr[node], end = rowptr[node + 1];
#pragma unroll 2
    for (int i = beg; i < end; ++i) {
        int s = ssrc[i];
        float w = swgt[i];
        acc = fmaf(w, h[(size_t)s * 64 + lane], acc);
    }
    out[(size_t)node * 64 + lane] = acc + bias[lane];
}

// ---------------------------------------------------------------------------
// Tiled f32 GEMM: C[M,N] = op(A)[M,K] @ B[K,N].  256 threads, BN == N.
// RELU applies relu to A elements on load (layer-2 input activation).
// ---------------------------------------------------------------------------
template <int BM, int BN, int BK, int TM, int TN, bool RELU>
__global__ __launch_bounds__(256) void gemm_kernel(const float* __restrict__ A,
                                                   const float* __restrict__ B,
                                                   float* __restrict__ C,
                                                   int M, int N, int K) {
    static_assert(TM == 4, "A fragment read assumes TM==4");
    static_assert((BM / TM) * (BN / TN) == 256, "need 256 threads");
    __shared__ float As[BK][BM];   // transposed A tile (k-major)
    __shared__ float Bs[BK][BN];

    const int tid = threadIdx.x;
    constexpr int CG = BN / TN;
    const int tx = tid % CG;
    const int ty = tid / CG;
    const int rowBase = blockIdx.x * BM;

    float acc[TM][TN];
#pragma unroll
    for (int i = 0; i < TM; i++)
#pragma unroll
        for (int j = 0; j < TN; j++) acc[i][j] = 0.0f;

    static_assert(BM * BK == 1024, "A staging mapping assumes BM*BK==1024");
    const int aRow = tid / (BK / 4);
    const int aK4  = tid % (BK / 4);
    int arow_g = rowBase + aRow;
    if (arow_g >= M) arow_g = M - 1;
    const float* Aptr = A + (size_t)arow_g * K + aK4 * 4;

    constexpr int BF4 = (BK * BN) / 1024;

    for (int k0 = 0; k0 < K; k0 += BK) {
        float4 av4 = *(const float4*)(Aptr + k0);
        if (RELU) {
            av4.x = fmaxf(av4.x, 0.0f); av4.y = fmaxf(av4.y, 0.0f);
            av4.z = fmaxf(av4.z, 0.0f); av4.w = fmaxf(av4.w, 0.0f);
        }
        As[aK4 * 4 + 0][aRow] = av4.x;
        As[aK4 * 4 + 1][aRow] = av4.y;
        As[aK4 * 4 + 2][aRow] = av4.z;
        As[aK4 * 4 + 3][aRow] = av4.w;
#pragma unroll
        for (int i = 0; i < BF4; i++) {
            int f4 = tid + i * 256;
            int br = f4 / (BN / 4);
            int bc = (f4 % (BN / 4)) * 4;
            *(float4*)&Bs[br][bc] = *(const float4*)(B + (size_t)(k0 + br) * N + bc);
        }
        __syncthreads();
#pragma unroll
        for (int k = 0; k < BK; k++) {
            float a[TM], b[TN];
            *(float4*)a = *(const float4*)&As[k][ty * TM];
#pragma unroll
            for (int j = 0; j < TN / 4; j++)
                *(float4*)(b + 4 * j) = *(const float4*)&Bs[k][tx * TN + 4 * j];
#pragma unroll
            for (int i = 0; i < TM; i++)
#pragma unroll
                for (int j = 0; j < TN; j++)
                    acc[i][j] = fmaf(a[i], b[j], acc[i][j]);
        }
        __syncthreads();
    }

#pragma unroll
    for (int i = 0; i < TM; i++) {
        int r = rowBase + ty * TM + i;
        if (r < M) {
#pragma unroll
            for (int j = 0; j < TN / 4; j++) {
                float4 o = make_float4(acc[i][4 * j + 0], acc[i][4 * j + 1],
                                       acc[i][4 * j + 2], acc[i][4 * j + 3]);
                *(float4*)(C + (size_t)r * N + tx * TN + 4 * j) = o;
            }
        }
    }
}

extern "C" void kernel_launch(void* const* d_in, const int* in_sizes, int n_in,
                              void* d_out, int out_size, void* d_ws, size_t ws_size,
                              hipStream_t stream) {
    const float* x  = (const float*)d_in[0];
    const int*   ei = (const int*)d_in[1];   // [2, E] flat: src row then dst row
    const float* W1 = (const float*)d_in[2];
    const float* b1 = (const float*)d_in[3];
    const float* W2 = (const float*)d_in[4];
    const float* b2 = (const float*)d_in[5];
    float* out = (float*)d_out;

    const int IN_C = 256, HID_C = 128, OUT_C = 64;
    const int N = in_sizes[0] / IN_C;
    const int E = in_sizes[1] / 2;
    const int* srcA = ei;
    const int* dstA = ei + E;

    char* ws = (char*)d_ws;
    const size_t KB = 1024, MB = 1024 * 1024;
    int*   counts = (int*)(ws);                   // N ints
    float* dinv   = (float*)(ws + 256 * KB);      // N floats
    int*   rowptr = (int*)(ws + 512 * KB);        // N+1 ints
    int*   cursor = (int*)(ws + 768 * KB);        // N ints
    int*   ssrc   = (int*)(ws + 1 * MB);          // E ints (3.2 MB)
    float* swgt   = (float*)(ws + 5 * MB);        // E floats (3.2 MB)
    float* h1     = (float*)(ws + 9 * MB);        // N*128 f (25.6 MB)
    float* a1     = (float*)(ws + 36 * MB);       // N*128 f (25.6 MB)
    float* h2     = h1;                           // reuse (N*64)

    const int nb256 = (N + 255) / 256;
    const int eb256 = (E + 255) / 256;

    // ---- CSR build (int atomics only) ----
    zero_int_kernel<<<nb256, 256, 0, stream>>>(counts, N);
    count_deg_kernel<<<eb256, 256, 0, stream>>>(dstA, counts, E);
    make_dinv_kernel<<<nb256, 256, 0, stream>>>(counts, dinv, N);
    scan_kernel<<<1, 256, 0, stream>>>(counts, rowptr, N);
    copy_int_kernel<<<nb256, 256, 0, stream>>>(rowptr, cursor, N);
    fill_kernel<<<eb256, 256, 0, stream>>>(srcA, dstA, dinv, cursor, ssrc, swgt, E);

    // ---- layer 1 ----
    gemm_kernel<64, 128, 16, 4, 8, false>
        <<<(N + 63) / 64, 256, 0, stream>>>(x, W1, h1, N, HID_C, IN_C);
    agg128_kernel<<<(N + 3) / 4, 256, 0, stream>>>(rowptr, ssrc, swgt, h1, dinv, b1, a1, N);

    // ---- layer 2 ----
    gemm_kernel<64, 64, 16, 4, 4, true>
        <<<(N + 63) / 64, 256, 0, stream>>>(a1, W2, h2, N, OUT_C, HID_C);
    agg64_kernel<<<(N + 3) / 4, 256, 0, stream>>>(rowptr, ssrc, swgt, h2, dinv, b2, out, N);
}

// Round 3
// 375.230 us; speedup vs baseline: 2.8058x; 1.3182x over previous
//
#include <hip/hip_runtime.h>

// ---------------------------------------------------------------------------
// 2-layer GCN forward on MI355X — round 3.
// R2 post-mortem: single-workgroup scan was 145 µs (29%) with 0.025% VALU —
// pure serialization. Replace with 3-phase hierarchical scan (49-way parallel).
// ---------------------------------------------------------------------------

__global__ void zero_int_kernel(int* __restrict__ p, int n) {
    int i = blockIdx.x * blockDim.x + threadIdx.x;
    if (i < n) p[i] = 0;
}

__global__ void copy_int_kernel(const int* __restrict__ a, int* __restrict__ b, int n) {
    int i = blockIdx.x * blockDim.x + threadIdx.x;
    if (i < n) b[i] = a[i];
}

__global__ void count_deg_kernel(const int* __restrict__ dst, int* __restrict__ counts, int e) {
    int i = blockIdx.x * blockDim.x + threadIdx.x;
    if (i < e) atomicAdd(&counts[dst[i]], 1);
}

// dinv[v] = rsqrt(indeg + 1 self-loop)
__global__ void make_dinv_kernel(const int* __restrict__ counts, float* __restrict__ dinv, int n) {
    int i = blockIdx.x * blockDim.x + threadIdx.x;
    if (i < n) dinv[i] = rsqrtf((float)counts[i] + 1.0f);
}

// ---- Hierarchical exclusive scan over counts[0..n) -> rowptr[0..n] ----
// ntot = n+1 logical elements (counts[n] := 0 so rowptr[n] = total).
// Phase A: per-1024-chunk sums.
__global__ __launch_bounds__(256) void scan_partial_kernel(const int* __restrict__ counts,
                                                           int* __restrict__ bsums, int n) {
    __shared__ int wsum[4];
    const int tid = threadIdx.x;
    const int lane = tid & 63, wv = tid >> 6;
    int base = blockIdx.x * 1024 + tid * 4;
    int s = 0;
#pragma unroll
    for (int j = 0; j < 4; j++) {
        int i = base + j;
        if (i < n) s += counts[i];
    }
#pragma unroll
    for (int off = 1; off < 64; off <<= 1) s += __shfl_up(s, off, 64) * (lane >= off ? 1 : 0);
    if (lane == 63) wsum[wv] = s;
    __syncthreads();
    if (tid == 0) bsums[blockIdx.x] = wsum[0] + wsum[1] + wsum[2] + wsum[3];
}

// Phase B: single-wave exclusive scan of block sums (in place).
__global__ void scan_bsums_kernel(int* __restrict__ bsums, int nb) {
    int lane = threadIdx.x;
    int carry = 0;
    for (int base = 0; base < nb; base += 64) {
        int i = base + lane;
        int v = (i < nb) ? bsums[i] : 0;
        int x = v;
#pragma unroll
        for (int off = 1; off < 64; off <<= 1) {
            int y = __shfl_up(x, off, 64);
            if (lane >= off) x += y;
        }
        if (i < nb) bsums[i] = carry + x - v;  // exclusive
        carry += __shfl(x, 63, 64);
    }
}

// Phase C: re-scan each chunk with carried offset; write rowptr[0..n].
__global__ __launch_bounds__(256) void scan_final_kernel(const int* __restrict__ counts,
                                                         const int* __restrict__ bsums,
                                                         int* __restrict__ rowptr, int n) {
    __shared__ int wsum[4];
    const int tid = threadIdx.x;
    const int lane = tid & 63, wv = tid >> 6;
    int base = blockIdx.x * 1024 + tid * 4;
    int v[4];
#pragma unroll
    for (int j = 0; j < 4; j++) {
        int i = base + j;
        v[j] = (i < n) ? counts[i] : 0;
    }
    int tot = v[0] + v[1] + v[2] + v[3];
    int x = tot;
#pragma unroll
    for (int off = 1; off < 64; off <<= 1) {
        int y = __shfl_up(x, off, 64);
        if (lane >= off) x += y;
    }
    if (lane == 63) wsum[wv] = x;
    __syncthreads();
    int wpre = 0;
    for (int k = 0; k < wv; k++) wpre += wsum[k];
    int pre = bsums[blockIdx.x] + wpre + (x - tot);
#pragma unroll
    for (int j = 0; j < 4; j++) {
        int i = base + j;
        if (i <= n) rowptr[i] = pre;
        pre += v[j];
    }
}

// Scatter edges into CSR order; precompute edge weight dinv[src]*dinv[dst].
__global__ void fill_kernel(const int* __restrict__ src, const int* __restrict__ dst,
                            const float* __restrict__ dinv, int* __restrict__ cursor,
                            int* __restrict__ ssrc, float* __restrict__ swgt, int e) {
    int i = blockIdx.x * blockDim.x + threadIdx.x;
    if (i >= e) return;
    int s = src[i], d = dst[i];
    int pos = atomicAdd(&cursor[d], 1);
    ssrc[pos] = s;
    swgt[pos] = dinv[s] * dinv[d];
}

// One wave per node, 128 channels (float2/lane): out = bias + dinv^2*h_self + sum w*h_src
__global__ __launch_bounds__(256) void agg128_kernel(
    const int* __restrict__ rowptr, const int* __restrict__ ssrc,
    const float* __restrict__ swgt, const float* __restrict__ h,
    const float* __restrict__ dinv, const float* __restrict__ bias,
    float* __restrict__ out, int n) {
    int node = blockIdx.x * 4 + (threadIdx.x >> 6);
    if (node >= n) return;
    int lane = threadIdx.x & 63;
    float di = dinv[node];
    float2 self = *((const float2*)(h + (size_t)node * 128) + lane);
    float accx = di * di * self.x;
    float accy = di * di * self.y;
    int beg = rowptr[node], end = rowptr[node + 1];
#pragma unroll 2
    for (int i = beg; i < end; ++i) {
        int s = ssrc[i];
        float w = swgt[i];
        float2 v = *((const float2*)(h + (size_t)s * 128) + lane);
        accx = fmaf(w, v.x, accx);
        accy = fmaf(w, v.y, accy);
    }
    float2 bv = *((const float2*)bias + lane);
    float2 o = make_float2(accx + bv.x, accy + bv.y);
    *((float2*)(out + (size_t)node * 128) + lane) = o;
}

// One wave per node, 64 channels (lane == channel)
__global__ __launch_bounds__(256) void agg64_kernel(
    const int* __restrict__ rowptr, const int* __restrict__ ssrc,
    const float* __restrict__ swgt, const float* __restrict__ h,
    const float* __restrict__ dinv, const float* __restrict__ bias,
    float* __restrict__ out, int n) {
    int node = blockIdx.x * 4 + (threadIdx.x >> 6);
    if (node >= n) return;
    int lane = threadIdx.x & 63;
    float di = dinv[node];
    float acc = di * di * h[(size_t)node * 64 + lane];
    int beg = rowptr[node], end = rowptr[node + 1];
#pragma unroll 2
    for (int i = beg; i < end; ++i) {
        int s = ssrc[i];
        float w = swgt[i];
        acc = fmaf(w, h[(size_t)s * 64 + lane], acc);
    }
    out[(size_t)node * 64 + lane] = acc + bias[lane];
}

// ---------------------------------------------------------------------------
// Tiled f32 GEMM: C[M,N] = op(A)[M,K] @ B[K,N].  256 threads, BN == N.
// RELU applies relu to A elements on load (layer-2 input activation).
// ---------------------------------------------------------------------------
template <int BM, int BN, int BK, int TM, int TN, bool RELU>
__global__ __launch_bounds__(256) void gemm_kernel(const float* __restrict__ A,
                                                   const float* __restrict__ B,
                                                   float* __restrict__ C,
                                                   int M, int N, int K) {
    static_assert(TM == 4, "A fragment read assumes TM==4");
    static_assert((BM / TM) * (BN / TN) == 256, "need 256 threads");
    __shared__ float As[BK][BM];   // transposed A tile (k-major)
    __shared__ float Bs[BK][BN];

    const int tid = threadIdx.x;
    constexpr int CG = BN / TN;
    const int tx = tid % CG;
    const int ty = tid / CG;
    const int rowBase = blockIdx.x * BM;

    float acc[TM][TN];
#pragma unroll
    for (int i = 0; i < TM; i++)
#pragma unroll
        for (int j = 0; j < TN; j++) acc[i][j] = 0.0f;

    static_assert(BM * BK == 1024, "A staging mapping assumes BM*BK==1024");
    const int aRow = tid / (BK / 4);
    const int aK4  = tid % (BK / 4);
    int arow_g = rowBase + aRow;
    if (arow_g >= M) arow_g = M - 1;
    const float* Aptr = A + (size_t)arow_g * K + aK4 * 4;

    constexpr int BF4 = (BK * BN) / 1024;

    for (int k0 = 0; k0 < K; k0 += BK) {
        float4 av4 = *(const float4*)(Aptr + k0);
        if (RELU) {
            av4.x = fmaxf(av4.x, 0.0f); av4.y = fmaxf(av4.y, 0.0f);
            av4.z = fmaxf(av4.z, 0.0f); av4.w = fmaxf(av4.w, 0.0f);
        }
        As[aK4 * 4 + 0][aRow] = av4.x;
        As[aK4 * 4 + 1][aRow] = av4.y;
        As[aK4 * 4 + 2][aRow] = av4.z;
        As[aK4 * 4 + 3][aRow] = av4.w;
#pragma unroll
        for (int i = 0; i < BF4; i++) {
            int f4 = tid + i * 256;
            int br = f4 / (BN / 4);
            int bc = (f4 % (BN / 4)) * 4;
            *(float4*)&Bs[br][bc] = *(const float4*)(B + (size_t)(k0 + br) * N + bc);
        }
        __syncthreads();
#pragma unroll
        for (int k = 0; k < BK; k++) {
            float a[TM], b[TN];
            *(float4*)a = *(const float4*)&As[k][ty * TM];
#pragma unroll
            for (int j = 0; j < TN / 4; j++)
                *(float4*)(b + 4 * j) = *(const float4*)&Bs[k][tx * TN + 4 * j];
#pragma unroll
            for (int i = 0; i < TM; i++)
#pragma unroll
                for (int j = 0; j < TN; j++)
                    acc[i][j] = fmaf(a[i], b[j], acc[i][j]);
        }
        __syncthreads();
    }

#pragma unroll
    for (int i = 0; i < TM; i++) {
        int r = rowBase + ty * TM + i;
        if (r < M) {
#pragma unroll
            for (int j = 0; j < TN / 4; j++) {
                float4 o = make_float4(acc[i][4 * j + 0], acc[i][4 * j + 1],
                                       acc[i][4 * j + 2], acc[i][4 * j + 3]);
                *(float4*)(C + (size_t)r * N + tx * TN + 4 * j) = o;
            }
        }
    }
}

extern "C" void kernel_launch(void* const* d_in, const int* in_sizes, int n_in,
                              void* d_out, int out_size, void* d_ws, size_t ws_size,
                              hipStream_t stream) {
    const float* x  = (const float*)d_in[0];
    const int*   ei = (const int*)d_in[1];   // [2, E] flat: src row then dst row
    const float* W1 = (const float*)d_in[2];
    const float* b1 = (const float*)d_in[3];
    const float* W2 = (const float*)d_in[4];
    const float* b2 = (const float*)d_in[5];
    float* out = (float*)d_out;

    const int IN_C = 256, HID_C = 128, OUT_C = 64;
    const int N = in_sizes[0] / IN_C;
    const int E = in_sizes[1] / 2;
    const int* srcA = ei;
    const int* dstA = ei + E;

    char* ws = (char*)d_ws;
    const size_t KB = 1024, MB = 1024 * 1024;
    int*   counts = (int*)(ws);                   // N ints
    float* dinv   = (float*)(ws + 256 * KB);      // N floats
    int*   rowptr = (int*)(ws + 512 * KB);        // N+1 ints
    int*   cursor = (int*)(ws + 768 * KB);        // N ints
    int*   bsums  = (int*)(ws + 960 * KB);        // ~64 ints
    int*   ssrc   = (int*)(ws + 1 * MB);          // E ints (3.2 MB)
    float* swgt   = (float*)(ws + 5 * MB);        // E floats (3.2 MB)
    float* h1     = (float*)(ws + 9 * MB);        // N*128 f (25.6 MB)
    float* a1     = (float*)(ws + 36 * MB);       // N*128 f (25.6 MB)
    float* h2     = h1;                           // reuse (N*64)

    const int nb256 = (N + 255) / 256;
    const int eb256 = (E + 255) / 256;
    const int nbScan = (N + 1 + 1023) / 1024;     // chunks covering 0..N inclusive

    // ---- CSR build (int atomics only) ----
    zero_int_kernel<<<nb256, 256, 0, stream>>>(counts, N);
    count_deg_kernel<<<eb256, 256, 0, stream>>>(dstA, counts, E);
    make_dinv_kernel<<<nb256, 256, 0, stream>>>(counts, dinv, N);
    scan_partial_kernel<<<nbScan, 256, 0, stream>>>(counts, bsums, N);
    scan_bsums_kernel<<<1, 64, 0, stream>>>(bsums, nbScan);
    scan_final_kernel<<<nbScan, 256, 0, stream>>>(counts, bsums, rowptr, N);
    copy_int_kernel<<<nb256, 256, 0, stream>>>(rowptr, cursor, N);
    fill_kernel<<<eb256, 256, 0, stream>>>(srcA, dstA, dinv, cursor, ssrc, swgt, E);

    // ---- layer 1 ----
    gemm_kernel<64, 128, 16, 4, 8, false>
        <<<(N + 63) / 64, 256, 0, stream>>>(x, W1, h1, N, HID_C, IN_C);
    agg128_kernel<<<(N + 3) / 4, 256, 0, stream>>>(rowptr, ssrc, swgt, h1, dinv, b1, a1, N);

    // ---- layer 2 ----
    gemm_kernel<64, 64, 16, 4, 4, true>
        <<<(N + 63) / 64, 256, 0, stream>>>(a1, W2, h2, N, OUT_C, HID_C);
    agg64_kernel<<<(N + 3) / 4, 256, 0, stream>>>(rowptr, ssrc, swgt, h2, dinv, b2, out, N);
}

// Round 4
// 357.917 us; speedup vs baseline: 2.9415x; 1.0484x over previous
//
#include <hip/hip_runtime.h>

// ---------------------------------------------------------------------------
// 2-layer GCN forward on MI355X — round 4.
// R3 post-mortem: agg128 = 65 µs, FETCH 189 MB (L3-path gather-byte bound).
// Change: store transformed features h in bf16 (RNE in GEMM epilogue) and
// gather bf16 rows -> halves gather traffic. a1 (GEMM2 input) and final out
// stay f32. Fused make_dinv into scan_partial, cursor-copy into scan_final.
// ---------------------------------------------------------------------------

__device__ __forceinline__ unsigned short f32_to_bf16_rne(float f) {
    unsigned u = __float_as_uint(f);
    return (unsigned short)((u + 0x7fffu + ((u >> 16) & 1u)) >> 16);
}

__global__ void zero_int_kernel(int* __restrict__ p, int n) {
    int i = blockIdx.x * blockDim.x + threadIdx.x;
    if (i < n) p[i] = 0;
}

__global__ void count_deg_kernel(const int* __restrict__ dst, int* __restrict__ counts, int e) {
    int i = blockIdx.x * blockDim.x + threadIdx.x;
    if (i < e) atomicAdd(&counts[dst[i]], 1);
}

// ---- Hierarchical exclusive scan over counts[0..n) -> rowptr[0..n] ----
// Phase A: per-1024-chunk sums; also emits dinv[i] = rsqrt(counts[i]+1).
__global__ __launch_bounds__(256) void scan_partial_kernel(const int* __restrict__ counts,
                                                           int* __restrict__ bsums,
                                                           float* __restrict__ dinv, int n) {
    __shared__ int wsum[4];
    const int tid = threadIdx.x;
    const int lane = tid & 63, wv = tid >> 6;
    int base = blockIdx.x * 1024 + tid * 4;
    int s = 0;
#pragma unroll
    for (int j = 0; j < 4; j++) {
        int i = base + j;
        if (i < n) {
            int c = counts[i];
            s += c;
            dinv[i] = rsqrtf((float)c + 1.0f);
        }
    }
#pragma unroll
    for (int off = 1; off < 64; off <<= 1) {
        int y = __shfl_up(s, off, 64);
        if (lane >= off) s += y;
    }
    if (lane == 63) wsum[wv] = s;
    __syncthreads();
    if (tid == 0) bsums[blockIdx.x] = wsum[0] + wsum[1] + wsum[2] + wsum[3];
}

// Phase B: single-wave exclusive scan of block sums (in place).
__global__ void scan_bsums_kernel(int* __restrict__ bsums, int nb) {
    int lane = threadIdx.x;
    int carry = 0;
    for (int base = 0; base < nb; base += 64) {
        int i = base + lane;
        int v = (i < nb) ? bsums[i] : 0;
        int x = v;
#pragma unroll
        for (int off = 1; off < 64; off <<= 1) {
            int y = __shfl_up(x, off, 64);
            if (lane >= off) x += y;
        }
        if (i < nb) bsums[i] = carry + x - v;  // exclusive
        carry += __shfl(x, 63, 64);
    }
}

// Phase C: re-scan each chunk with carried offset; write rowptr[0..n] and cursor.
__global__ __launch_bounds__(256) void scan_final_kernel(const int* __restrict__ counts,
                                                         const int* __restrict__ bsums,
                                                         int* __restrict__ rowptr,
                                                         int* __restrict__ cursor, int n) {
    __shared__ int wsum[4];
    const int tid = threadIdx.x;
    const int lane = tid & 63, wv = tid >> 6;
    int base = blockIdx.x * 1024 + tid * 4;
    int v[4];
#pragma unroll
    for (int j = 0; j < 4; j++) {
        int i = base + j;
        v[j] = (i < n) ? counts[i] : 0;
    }
    int tot = v[0] + v[1] + v[2] + v[3];
    int x = tot;
#pragma unroll
    for (int off = 1; off < 64; off <<= 1) {
        int y = __shfl_up(x, off, 64);
        if (lane >= off) x += y;
    }
    if (lane == 63) wsum[wv] = x;
    __syncthreads();
    int wpre = 0;
    for (int k = 0; k < wv; k++) wpre += wsum[k];
    int pre = bsums[blockIdx.x] + wpre + (x - tot);
#pragma unroll
    for (int j = 0; j < 4; j++) {
        int i = base + j;
        if (i <= n) rowptr[i] = pre;
        if (i < n) cursor[i] = pre;
        pre += v[j];
    }
}

// Scatter edges into CSR order; precompute edge weight dinv[src]*dinv[dst].
__global__ void fill_kernel(const int* __restrict__ src, const int* __restrict__ dst,
                            const float* __restrict__ dinv, int* __restrict__ cursor,
                            int* __restrict__ ssrc, float* __restrict__ swgt, int e) {
    int i = blockIdx.x * blockDim.x + threadIdx.x;
    if (i >= e) return;
    int s = src[i], d = dst[i];
    int pos = atomicAdd(&cursor[d], 1);
    ssrc[pos] = s;
    swgt[pos] = dinv[s] * dinv[d];
}

// One wave per node, 128 bf16 channels (uint/lane = 2 channels).
// out(f32) = bias + dinv^2*h_self + sum w*h_src
__global__ __launch_bounds__(256) void agg128_kernel(
    const int* __restrict__ rowptr, const int* __restrict__ ssrc,
    const float* __restrict__ swgt, const unsigned short* __restrict__ hb,
    const float* __restrict__ dinv, const float* __restrict__ bias,
    float* __restrict__ out, int n) {
    int node = blockIdx.x * 4 + (threadIdx.x >> 6);
    if (node >= n) return;
    int lane = threadIdx.x & 63;
    float di = dinv[node];
    unsigned sv = ((const unsigned*)(hb + (size_t)node * 128))[lane];
    float accx = di * di * __uint_as_float(sv << 16);
    float accy = di * di * __uint_as_float(sv & 0xffff0000u);
    int beg = rowptr[node], end = rowptr[node + 1];
#pragma unroll 2
    for (int i = beg; i < end; ++i) {
        int s = ssrc[i];
        float w = swgt[i];
        unsigned v = ((const unsigned*)(hb + (size_t)s * 128))[lane];
        accx = fmaf(w, __uint_as_float(v << 16), accx);
        accy = fmaf(w, __uint_as_float(v & 0xffff0000u), accy);
    }
    float2 bv = *((const float2*)bias + lane);
    *((float2*)(out + (size_t)node * 128) + lane) = make_float2(accx + bv.x, accy + bv.y);
}

// One wave per node, 64 bf16 channels (lane == channel).
__global__ __launch_bounds__(256) void agg64_kernel(
    const int* __restrict__ rowptr, const int* __restrict__ ssrc,
    const float* __restrict__ swgt, const unsigned short* __restrict__ hb,
    const float* __restrict__ dinv, const float* __restrict__ bias,
    float* __restrict__ out, int n) {
    int node = blockIdx.x * 4 + (threadIdx.x >> 6);
    if (node >= n) return;
    int lane = threadIdx.x & 63;
    float di = dinv[node];
    float self = __uint_as_float((unsigned)hb[(size_t)node * 64 + lane] << 16);
    float acc = di * di * self;
    int beg = rowptr[node], end = rowptr[node + 1];
#pragma unroll 2
    for (int i = beg; i < end; ++i) {
        int s = ssrc[i];
        float w = swgt[i];
        float v = __uint_as_float((unsigned)hb[(size_t)s * 64 + lane] << 16);
        acc = fmaf(w, v, acc);
    }
    out[(size_t)node * 64 + lane] = acc + bias[lane];
}

// ---------------------------------------------------------------------------
// Tiled f32 GEMM: C[M,N] = op(A)[M,K] @ B[K,N].  256 threads, BN == N.
// RELU applies relu to A on load.  OBF16: store C as bf16 (RNE).
// ---------------------------------------------------------------------------
template <int BM, int BN, int BK, int TM, int TN, bool RELU, bool OBF16>
__global__ __launch_bounds__(256) void gemm_kernel(const float* __restrict__ A,
                                                   const float* __restrict__ B,
                                                   void* __restrict__ Cv,
                                                   int M, int N, int K) {
    static_assert(TM == 4, "A fragment read assumes TM==4");
    static_assert((BM / TM) * (BN / TN) == 256, "need 256 threads");
    __shared__ float As[BK][BM];   // transposed A tile (k-major)
    __shared__ float Bs[BK][BN];

    const int tid = threadIdx.x;
    constexpr int CG = BN / TN;
    const int tx = tid % CG;
    const int ty = tid / CG;
    const int rowBase = blockIdx.x * BM;

    float acc[TM][TN];
#pragma unroll
    for (int i = 0; i < TM; i++)
#pragma unroll
        for (int j = 0; j < TN; j++) acc[i][j] = 0.0f;

    static_assert(BM * BK == 1024, "A staging mapping assumes BM*BK==1024");
    const int aRow = tid / (BK / 4);
    const int aK4  = tid % (BK / 4);
    int arow_g = rowBase + aRow;
    if (arow_g >= M) arow_g = M - 1;
    const float* Aptr = A + (size_t)arow_g * K + aK4 * 4;

    constexpr int BF4 = (BK * BN) / 1024;

    for (int k0 = 0; k0 < K; k0 += BK) {
        float4 av4 = *(const float4*)(Aptr + k0);
        if (RELU) {
            av4.x = fmaxf(av4.x, 0.0f); av4.y = fmaxf(av4.y, 0.0f);
            av4.z = fmaxf(av4.z, 0.0f); av4.w = fmaxf(av4.w, 0.0f);
        }
        As[aK4 * 4 + 0][aRow] = av4.x;
        As[aK4 * 4 + 1][aRow] = av4.y;
        As[aK4 * 4 + 2][aRow] = av4.z;
        As[aK4 * 4 + 3][aRow] = av4.w;
#pragma unroll
        for (int i = 0; i < BF4; i++) {
            int f4 = tid + i * 256;
            int br = f4 / (BN / 4);
            int bc = (f4 % (BN / 4)) * 4;
            *(float4*)&Bs[br][bc] = *(const float4*)(B + (size_t)(k0 + br) * N + bc);
        }
        __syncthreads();
#pragma unroll
        for (int k = 0; k < BK; k++) {
            float a[TM], b[TN];
            *(float4*)a = *(const float4*)&As[k][ty * TM];
#pragma unroll
            for (int j = 0; j < TN / 4; j++)
                *(float4*)(b + 4 * j) = *(const float4*)&Bs[k][tx * TN + 4 * j];
#pragma unroll
            for (int i = 0; i < TM; i++)
#pragma unroll
                for (int j = 0; j < TN; j++)
                    acc[i][j] = fmaf(a[i], b[j], acc[i][j]);
        }
        __syncthreads();
    }

#pragma unroll
    for (int i = 0; i < TM; i++) {
        int r = rowBase + ty * TM + i;
        if (r < M) {
            if constexpr (OBF16) {
                union { unsigned short s[TN]; uint4 v4; uint2 v2; } ob;
#pragma unroll
                for (int j = 0; j < TN; j++) ob.s[j] = f32_to_bf16_rne(acc[i][j]);
                unsigned short* Crow = (unsigned short*)Cv + (size_t)r * N + tx * TN;
                if constexpr (TN == 8) *(uint4*)Crow = ob.v4;
                else *(uint2*)Crow = ob.v2;
            } else {
                float* Crow = (float*)Cv + (size_t)r * N + tx * TN;
#pragma unroll
                for (int j = 0; j < TN / 4; j++) {
                    float4 o = make_float4(acc[i][4 * j + 0], acc[i][4 * j + 1],
                                           acc[i][4 * j + 2], acc[i][4 * j + 3]);
                    *(float4*)(Crow + 4 * j) = o;
                }
            }
        }
    }
}

extern "C" void kernel_launch(void* const* d_in, const int* in_sizes, int n_in,
                              void* d_out, int out_size, void* d_ws, size_t ws_size,
                              hipStream_t stream) {
    const float* x  = (const float*)d_in[0];
    const int*   ei = (const int*)d_in[1];   // [2, E] flat: src row then dst row
    const float* W1 = (const float*)d_in[2];
    const float* b1 = (const float*)d_in[3];
    const float* W2 = (const float*)d_in[4];
    const float* b2 = (const float*)d_in[5];
    float* out = (float*)d_out;

    const int IN_C = 256, HID_C = 128, OUT_C = 64;
    const int N = in_sizes[0] / IN_C;
    const int E = in_sizes[1] / 2;
    const int* srcA = ei;
    const int* dstA = ei + E;

    char* ws = (char*)d_ws;
    const size_t KB = 1024, MB = 1024 * 1024;
    int*            counts = (int*)(ws);               // N ints
    float*          dinv   = (float*)(ws + 256 * KB);  // N floats
    int*            rowptr = (int*)(ws + 512 * KB);    // N+1 ints
    int*            cursor = (int*)(ws + 768 * KB);    // N ints
    int*            bsums  = (int*)(ws + 992 * KB);    // ~64 ints
    int*            ssrc   = (int*)(ws + 1 * MB);      // E ints (3.2 MB)
    float*          swgt   = (float*)(ws + 5 * MB);    // E floats (3.2 MB)
    unsigned short* h1b    = (unsigned short*)(ws + 9 * MB);   // N*128 bf16 (12.8 MB)
    float*          a1     = (float*)(ws + 23 * MB);   // N*128 f32 (25.6 MB)
    unsigned short* h2b    = h1b;                      // reuse (N*64 bf16)

    const int nb256 = (N + 255) / 256;
    const int eb256 = (E + 255) / 256;
    const int nbScan = (N + 1 + 1023) / 1024;

    // ---- CSR build (int atomics only) ----
    zero_int_kernel<<<nb256, 256, 0, stream>>>(counts, N);
    count_deg_kernel<<<eb256, 256, 0, stream>>>(dstA, counts, E);
    scan_partial_kernel<<<nbScan, 256, 0, stream>>>(counts, bsums, dinv, N);
    scan_bsums_kernel<<<1, 64, 0, stream>>>(bsums, nbScan);
    scan_final_kernel<<<nbScan, 256, 0, stream>>>(counts, bsums, rowptr, cursor, N);
    fill_kernel<<<eb256, 256, 0, stream>>>(srcA, dstA, dinv, cursor, ssrc, swgt, E);

    // ---- layer 1 ----
    gemm_kernel<64, 128, 16, 4, 8, false, true>
        <<<(N + 63) / 64, 256, 0, stream>>>(x, W1, h1b, N, HID_C, IN_C);
    agg128_kernel<<<(N + 3) / 4, 256, 0, stream>>>(rowptr, ssrc, swgt, h1b, dinv, b1, a1, N);

    // ---- layer 2 ----
    gemm_kernel<64, 64, 16, 4, 4, true, true>
        <<<(N + 63) / 64, 256, 0, stream>>>(a1, W2, h2b, N, OUT_C, HID_C);
    agg64_kernel<<<(N + 3) / 4, 256, 0, stream>>>(rowptr, ssrc, swgt, h2b, dinv, b2, out, N);
}

// Round 5
// 329.164 us; speedup vs baseline: 3.1985x; 1.0874x over previous
//
#include <hip/hip_runtime.h>
#include <hip/hip_bf16.h>

// ---------------------------------------------------------------------------
// 2-layer GCN forward on MI355X — round 5.
// R4 post-mortem: f32 VALU GEMM1 = 62 µs (53 TF, bank conflicts, low occ).
// Change: MFMA bf16 GEMMs (16x16x32, f32 acc), LDS-free: per-wave 16 rows,
// A packed f32->bf16 in registers, B pre-transposed bf16 (L1/L2-hot).
// Also: CSR edge records packed to int2 (src, bf32 weight) — one store/load.
// ---------------------------------------------------------------------------

typedef __attribute__((ext_vector_type(8))) short short8;
typedef __attribute__((ext_vector_type(4))) float f32x4;

union BF8 {
    short8 s;
    uint4 u;
    __hip_bfloat162 h[4];
};

__device__ __forceinline__ unsigned short f32_to_bf16_rne(float f) {
    unsigned u = __float_as_uint(f);
    return (unsigned short)((u + 0x7fffu + ((u >> 16) & 1u)) >> 16);
}

__global__ void zero_int_kernel(int* __restrict__ p, int n) {
    int i = blockIdx.x * blockDim.x + threadIdx.x;
    if (i < n) p[i] = 0;
}

__global__ void count_deg_kernel(const int* __restrict__ dst, int* __restrict__ counts, int e) {
    int i = blockIdx.x * blockDim.x + threadIdx.x;
    if (i < e) atomicAdd(&counts[dst[i]], 1);
}

// Transpose + convert W[K][N] f32 -> WT[N][K] bf16.
__global__ void wtrans_kernel(const float* __restrict__ W, unsigned short* __restrict__ WT,
                              int K, int N) {
    int i = blockIdx.x * blockDim.x + threadIdx.x;
    if (i >= K * N) return;
    int k = i / N, n = i % N;
    WT[n * K + k] = f32_to_bf16_rne(W[i]);
}

// ---- Hierarchical exclusive scan over counts[0..n) -> rowptr[0..n] ----
__global__ __launch_bounds__(256) void scan_partial_kernel(const int* __restrict__ counts,
                                                           int* __restrict__ bsums,
                                                           float* __restrict__ dinv, int n) {
    __shared__ int wsum[4];
    const int tid = threadIdx.x;
    const int lane = tid & 63, wv = tid >> 6;
    int base = blockIdx.x * 1024 + tid * 4;
    int s = 0;
#pragma unroll
    for (int j = 0; j < 4; j++) {
        int i = base + j;
        if (i < n) {
            int c = counts[i];
            s += c;
            dinv[i] = rsqrtf((float)c + 1.0f);
        }
    }
#pragma unroll
    for (int off = 1; off < 64; off <<= 1) {
        int y = __shfl_up(s, off, 64);
        if (lane >= off) s += y;
    }
    if (lane == 63) wsum[wv] = s;
    __syncthreads();
    if (tid == 0) bsums[blockIdx.x] = wsum[0] + wsum[1] + wsum[2] + wsum[3];
}

__global__ void scan_bsums_kernel(int* __restrict__ bsums, int nb) {
    int lane = threadIdx.x;
    int carry = 0;
    for (int base = 0; base < nb; base += 64) {
        int i = base + lane;
        int v = (i < nb) ? bsums[i] : 0;
        int x = v;
#pragma unroll
        for (int off = 1; off < 64; off <<= 1) {
            int y = __shfl_up(x, off, 64);
            if (lane >= off) x += y;
        }
        if (i < nb) bsums[i] = carry + x - v;  // exclusive
        carry += __shfl(x, 63, 64);
    }
}

__global__ __launch_bounds__(256) void scan_final_kernel(const int* __restrict__ counts,
                                                         const int* __restrict__ bsums,
                                                         int* __restrict__ rowptr,
                                                         int* __restrict__ cursor, int n) {
    __shared__ int wsum[4];
    const int tid = threadIdx.x;
    const int lane = tid & 63, wv = tid >> 6;
    int base = blockIdx.x * 1024 + tid * 4;
    int v[4];
#pragma unroll
    for (int j = 0; j < 4; j++) {
        int i = base + j;
        v[j] = (i < n) ? counts[i] : 0;
    }
    int tot = v[0] + v[1] + v[2] + v[3];
    int x = tot;
#pragma unroll
    for (int off = 1; off < 64; off <<= 1) {
        int y = __shfl_up(x, off, 64);
        if (lane >= off) x += y;
    }
    if (lane == 63) wsum[wv] = x;
    __syncthreads();
    int wpre = 0;
    for (int k = 0; k < wv; k++) wpre += wsum[k];
    int pre = bsums[blockIdx.x] + wpre + (x - tot);
#pragma unroll
    for (int j = 0; j < 4; j++) {
        int i = base + j;
        if (i <= n) rowptr[i] = pre;
        if (i < n) cursor[i] = pre;
        pre += v[j];
    }
}

// Scatter edges into CSR order; record = (src, bits(dinv[src]*dinv[dst])).
__global__ void fill_kernel(const int* __restrict__ src, const int* __restrict__ dst,
                            const float* __restrict__ dinv, int* __restrict__ cursor,
                            int2* __restrict__ sedge, int e) {
    int i = blockIdx.x * blockDim.x + threadIdx.x;
    if (i >= e) return;
    int s = src[i], d = dst[i];
    int pos = atomicAdd(&cursor[d], 1);
    sedge[pos] = make_int2(s, __float_as_int(dinv[s] * dinv[d]));
}

// One wave per node, 128 bf16 channels (uint/lane = 2 channels).
__global__ __launch_bounds__(256) void agg128_kernel(
    const int* __restrict__ rowptr, const int2* __restrict__ sedge,
    const unsigned short* __restrict__ hb, const float* __restrict__ dinv,
    const float* __restrict__ bias, float* __restrict__ out, int n) {
    int node = blockIdx.x * 4 + (threadIdx.x >> 6);
    if (node >= n) return;
    int lane = threadIdx.x & 63;
    float di = dinv[node];
    unsigned sv = ((const unsigned*)(hb + (size_t)node * 128))[lane];
    float accx = di * di * __uint_as_float(sv << 16);
    float accy = di * di * __uint_as_float(sv & 0xffff0000u);
    int beg = rowptr[node], end = rowptr[node + 1];
#pragma unroll 2
    for (int i = beg; i < end; ++i) {
        int2 e = sedge[i];
        float w = __int_as_float(e.y);
        unsigned v = ((const unsigned*)(hb + (size_t)e.x * 128))[lane];
        accx = fmaf(w, __uint_as_float(v << 16), accx);
        accy = fmaf(w, __uint_as_float(v & 0xffff0000u), accy);
    }
    float2 bv = *((const float2*)bias + lane);
    *((float2*)(out + (size_t)node * 128) + lane) = make_float2(accx + bv.x, accy + bv.y);
}

// One wave per node, 64 bf16 channels (lane == channel).
__global__ __launch_bounds__(256) void agg64_kernel(
    const int* __restrict__ rowptr, const int2* __restrict__ sedge,
    const unsigned short* __restrict__ hb, const float* __restrict__ dinv,
    const float* __restrict__ bias, float* __restrict__ out, int n) {
    int node = blockIdx.x * 4 + (threadIdx.x >> 6);
    if (node >= n) return;
    int lane = threadIdx.x & 63;
    float di = dinv[node];
    float self = __uint_as_float((unsigned)hb[(size_t)node * 64 + lane] << 16);
    float acc = di * di * self;
    int beg = rowptr[node], end = rowptr[node + 1];
#pragma unroll 2
    for (int i = beg; i < end; ++i) {
        int2 e = sedge[i];
        float w = __int_as_float(e.y);
        float v = __uint_as_float((unsigned)hb[(size_t)e.x * 64 + lane] << 16);
        acc = fmaf(w, v, acc);
    }
    out[(size_t)node * 64 + lane] = acc + bias[lane];
}

// ---------------------------------------------------------------------------
// MFMA bf16 GEMM: C[M,N] = bf16(op(A[M,K] f32)) @ bf16(B[K,N]), C bf16.
// BT is pre-transposed bf16 [N][K]. Block = 4 waves, wave owns 16 rows x N.
// No LDS, no barriers. Fragment layouts (verified m89/m91/m120):
//   A: lane holds A[m=lane&15][k=quad*8+j]  (8 contiguous k)
//   B: lane holds B[k=quad*8+j][n=lane&15]  -> contiguous in BT[n][k]
//   D: col=lane&15, row=quad*4+reg
// ---------------------------------------------------------------------------
template <int NT, int KS, bool RELU>
__global__ __launch_bounds__(256) void mfma_gemm_kernel(
    const float* __restrict__ A, const unsigned short* __restrict__ BT,
    unsigned short* __restrict__ C, int M) {
    constexpr int N = NT * 16;
    constexpr int K = KS * 32;
    const int tid = threadIdx.x;
    const int wave = tid >> 6, lane = tid & 63;
    const int quad = lane >> 4, m16 = lane & 15;
    const int rowBase = blockIdx.x * 64 + wave * 16;

    int rowA = rowBase + m16;
    if (rowA >= M) rowA = M - 1;                 // clamped load; stores guarded
    const float* Arow = A + (size_t)rowA * K;
    const unsigned short* Bbase = BT + (size_t)m16 * K + quad * 8;

    f32x4 acc[NT];
#pragma unroll
    for (int nt = 0; nt < NT; nt++) acc[nt] = f32x4{0.f, 0.f, 0.f, 0.f};

#pragma unroll
    for (int ks = 0; ks < KS; ks++) {
        const int k0 = ks * 32 + quad * 8;
        f32x4 a0 = *(const f32x4*)(Arow + k0);
        f32x4 a1 = *(const f32x4*)(Arow + k0 + 4);
        if (RELU) {
            a0.x = fmaxf(a0.x, 0.f); a0.y = fmaxf(a0.y, 0.f);
            a0.z = fmaxf(a0.z, 0.f); a0.w = fmaxf(a0.w, 0.f);
            a1.x = fmaxf(a1.x, 0.f); a1.y = fmaxf(a1.y, 0.f);
            a1.z = fmaxf(a1.z, 0.f); a1.w = fmaxf(a1.w, 0.f);
        }
        BF8 af;
        af.h[0] = __float22bfloat162_rn(make_float2(a0.x, a0.y));
        af.h[1] = __float22bfloat162_rn(make_float2(a0.z, a0.w));
        af.h[2] = __float22bfloat162_rn(make_float2(a1.x, a1.y));
        af.h[3] = __float22bfloat162_rn(make_float2(a1.z, a1.w));
#pragma unroll
        for (int nt = 0; nt < NT; nt++) {
            BF8 bf;
            bf.u = *(const uint4*)(Bbase + (size_t)nt * 16 * K + ks * 32);
            acc[nt] = __builtin_amdgcn_mfma_f32_16x16x32_bf16(af.s, bf.s, acc[nt], 0, 0, 0);
        }
    }

#pragma unroll
    for (int nt = 0; nt < NT; nt++) {
#pragma unroll
        for (int r = 0; r < 4; r++) {
            int row = rowBase + quad * 4 + r;
            if (row < M)
                C[(size_t)row * N + nt * 16 + m16] = f32_to_bf16_rne(acc[nt][r]);
        }
    }
}

extern "C" void kernel_launch(void* const* d_in, const int* in_sizes, int n_in,
                              void* d_out, int out_size, void* d_ws, size_t ws_size,
                              hipStream_t stream) {
    const float* x  = (const float*)d_in[0];
    const int*   ei = (const int*)d_in[1];   // [2, E] flat: src row then dst row
    const float* W1 = (const float*)d_in[2];
    const float* b1 = (const float*)d_in[3];
    const float* W2 = (const float*)d_in[4];
    const float* b2 = (const float*)d_in[5];
    float* out = (float*)d_out;

    const int IN_C = 256, HID_C = 128, OUT_C = 64;
    const int N = in_sizes[0] / IN_C;
    const int E = in_sizes[1] / 2;
    const int* srcA = ei;
    const int* dstA = ei + E;

    char* ws = (char*)d_ws;
    const size_t KB = 1024, MB = 1024 * 1024;
    int*            counts = (int*)(ws);                    // N ints
    float*          dinv   = (float*)(ws + 256 * KB);       // N floats
    int*            rowptr = (int*)(ws + 512 * KB);         // N+1 ints
    int*            cursor = (int*)(ws + 768 * KB);         // N ints
    int*            bsums  = (int*)(ws + 992 * KB);         // ~64 ints
    unsigned short* w1t    = (unsigned short*)(ws + 1 * MB);        // 128x256 bf16 (64 KB)
    unsigned short* w2t    = (unsigned short*)(ws + 1 * MB + 64 * KB); // 64x128 bf16 (16 KB)
    int2*           sedge  = (int2*)(ws + 2 * MB);          // E int2 (6.4 MB)
    unsigned short* h1b    = (unsigned short*)(ws + 9 * MB); // N*128 bf16 (12.8 MB)
    float*          a1     = (float*)(ws + 22 * MB);        // N*128 f32 (25.6 MB)
    unsigned short* h2b    = h1b;                           // reuse (N*64 bf16)

    const int nb256 = (N + 255) / 256;
    const int eb256 = (E + 255) / 256;
    const int nbScan = (N + 1 + 1023) / 1024;
    const int gGemm = (N + 63) / 64;

    // ---- CSR build + weight prep ----
    zero_int_kernel<<<nb256, 256, 0, stream>>>(counts, N);
    count_deg_kernel<<<eb256, 256, 0, stream>>>(dstA, counts, E);
    wtrans_kernel<<<(IN_C * HID_C + 255) / 256, 256, 0, stream>>>(W1, w1t, IN_C, HID_C);
    wtrans_kernel<<<(HID_C * OUT_C + 255) / 256, 256, 0, stream>>>(W2, w2t, HID_C, OUT_C);
    scan_partial_kernel<<<nbScan, 256, 0, stream>>>(counts, bsums, dinv, N);
    scan_bsums_kernel<<<1, 64, 0, stream>>>(bsums, nbScan);
    scan_final_kernel<<<nbScan, 256, 0, stream>>>(counts, bsums, rowptr, cursor, N);
    fill_kernel<<<eb256, 256, 0, stream>>>(srcA, dstA, dinv, cursor, sedge, E);

    // ---- layer 1: h1 = bf16(x) @ bf16(W1) ----
    mfma_gemm_kernel<8, 8, false><<<gGemm, 256, 0, stream>>>(x, w1t, h1b, N);
    agg128_kernel<<<(N + 3) / 4, 256, 0, stream>>>(rowptr, sedge, h1b, dinv, b1, a1, N);

    // ---- layer 2: h2 = bf16(relu(a1)) @ bf16(W2) ----
    mfma_gemm_kernel<4, 4, true><<<gGemm, 256, 0, stream>>>(a1, w2t, h2b, N);
    agg64_kernel<<<(N + 3) / 4, 256, 0, stream>>>(rowptr, sedge, h2b, dinv, b2, out, N);
}

// Round 6
// 299.543 us; speedup vs baseline: 3.5148x; 1.0989x over previous
//
#include <hip/hip_runtime.h>
#include <hip/hip_bf16.h>

// ---------------------------------------------------------------------------
// 2-layer GCN forward on MI355X — round 6.
// R5 post-mortem: agg128 = 52.9 µs, ~40 cyc/edge vs ~17 issue floor -> MLP
// (latency) bound with unroll 2. Changes:
//  (1) agg kernels: manual 4-wide edge batching (4 gathers in flight).
//  (2) agg128 folds bias+ReLU, stores a1 as bf16 (only consumer is GEMM2's
//      bf16 MFMA) -> halves a1 write + GEMM2 A-read; GEMM2 loses cvt/relu.
//  (3) single wtrans launch for both weights.
// ---------------------------------------------------------------------------

typedef __attribute__((ext_vector_type(8))) short short8;
typedef __attribute__((ext_vector_type(4))) float f32x4;

union BF8 {
    short8 s;
    uint4 u;
    __hip_bfloat162 h[4];
};

__device__ __forceinline__ unsigned short f32_to_bf16_rne(float f) {
    unsigned u = __float_as_uint(f);
    return (unsigned short)((u + 0x7fffu + ((u >> 16) & 1u)) >> 16);
}
__device__ __forceinline__ float bf_lo(unsigned v) { return __uint_as_float(v << 16); }
__device__ __forceinline__ float bf_hi(unsigned v) { return __uint_as_float(v & 0xffff0000u); }

__global__ void zero_int_kernel(int* __restrict__ p, int n) {
    int i = blockIdx.x * blockDim.x + threadIdx.x;
    if (i < n) p[i] = 0;
}

__global__ void count_deg_kernel(const int* __restrict__ dst, int* __restrict__ counts, int e) {
    int i = blockIdx.x * blockDim.x + threadIdx.x;
    if (i < e) atomicAdd(&counts[dst[i]], 1);
}

// Transpose+convert both weights in one launch.
// W1[256][128] -> w1t[128][256] bf16 ; W2[128][64] -> w2t[64][128] bf16.
__global__ void wtrans_kernel(const float* __restrict__ W1, const float* __restrict__ W2,
                              unsigned short* __restrict__ w1t, unsigned short* __restrict__ w2t) {
    int i = blockIdx.x * blockDim.x + threadIdx.x;
    if (i < 256 * 128) {
        int k = i / 128, n = i % 128;
        w1t[n * 256 + k] = f32_to_bf16_rne(W1[i]);
    } else {
        int j = i - 256 * 128;
        if (j < 128 * 64) {
            int k = j / 64, n = j % 64;
            w2t[n * 128 + k] = f32_to_bf16_rne(W2[j]);
        }
    }
}

// ---- Hierarchical exclusive scan over counts[0..n) -> rowptr[0..n] ----
__global__ __launch_bounds__(256) void scan_partial_kernel(const int* __restrict__ counts,
                                                           int* __restrict__ bsums,
                                                           float* __restrict__ dinv, int n) {
    __shared__ int wsum[4];
    const int tid = threadIdx.x;
    const int lane = tid & 63, wv = tid >> 6;
    int base = blockIdx.x * 1024 + tid * 4;
    int s = 0;
#pragma unroll
    for (int j = 0; j < 4; j++) {
        int i = base + j;
        if (i < n) {
            int c = counts[i];
            s += c;
            dinv[i] = rsqrtf((float)c + 1.0f);
        }
    }
#pragma unroll
    for (int off = 1; off < 64; off <<= 1) {
        int y = __shfl_up(s, off, 64);
        if (lane >= off) s += y;
    }
    if (lane == 63) wsum[wv] = s;
    __syncthreads();
    if (tid == 0) bsums[blockIdx.x] = wsum[0] + wsum[1] + wsum[2] + wsum[3];
}

__global__ void scan_bsums_kernel(int* __restrict__ bsums, int nb) {
    int lane = threadIdx.x;
    int carry = 0;
    for (int base = 0; base < nb; base += 64) {
        int i = base + lane;
        int v = (i < nb) ? bsums[i] : 0;
        int x = v;
#pragma unroll
        for (int off = 1; off < 64; off <<= 1) {
            int y = __shfl_up(x, off, 64);
            if (lane >= off) x += y;
        }
        if (i < nb) bsums[i] = carry + x - v;  // exclusive
        carry += __shfl(x, 63, 64);
    }
}

__global__ __launch_bounds__(256) void scan_final_kernel(const int* __restrict__ counts,
                                                         const int* __restrict__ bsums,
                                                         int* __restrict__ rowptr,
                                                         int* __restrict__ cursor, int n) {
    __shared__ int wsum[4];
    const int tid = threadIdx.x;
    const int lane = tid & 63, wv = tid >> 6;
    int base = blockIdx.x * 1024 + tid * 4;
    int v[4];
#pragma unroll
    for (int j = 0; j < 4; j++) {
        int i = base + j;
        v[j] = (i < n) ? counts[i] : 0;
    }
    int tot = v[0] + v[1] + v[2] + v[3];
    int x = tot;
#pragma unroll
    for (int off = 1; off < 64; off <<= 1) {
        int y = __shfl_up(x, off, 64);
        if (lane >= off) x += y;
    }
    if (lane == 63) wsum[wv] = x;
    __syncthreads();
    int wpre = 0;
    for (int k = 0; k < wv; k++) wpre += wsum[k];
    int pre = bsums[blockIdx.x] + wpre + (x - tot);
#pragma unroll
    for (int j = 0; j < 4; j++) {
        int i = base + j;
        if (i <= n) rowptr[i] = pre;
        if (i < n) cursor[i] = pre;
        pre += v[j];
    }
}

// Scatter edges into CSR order; record = (src, bits(dinv[src]*dinv[dst])).
__global__ void fill_kernel(const int* __restrict__ src, const int* __restrict__ dst,
                            const float* __restrict__ dinv, int* __restrict__ cursor,
                            int2* __restrict__ sedge, int e) {
    int i = blockIdx.x * blockDim.x + threadIdx.x;
    if (i >= e) return;
    int s = src[i], d = dst[i];
    int pos = atomicAdd(&cursor[d], 1);
    sedge[pos] = make_int2(s, __float_as_int(dinv[s] * dinv[d]));
}

// One wave per node, 128 bf16 channels (uint/lane = 2 channels).
// Writes a1 = bf16(relu(bias + dinv^2*h_self + sum w*h_src)).
__global__ __launch_bounds__(256) void agg128_kernel(
    const int* __restrict__ rowptr, const int2* __restrict__ sedge,
    const unsigned short* __restrict__ hb, const float* __restrict__ dinv,
    const float* __restrict__ bias, unsigned short* __restrict__ outb, int n) {
    int node = blockIdx.x * 4 + (threadIdx.x >> 6);
    if (node >= n) return;
    int lane = threadIdx.x & 63;
    float di = dinv[node];
    unsigned sv = ((const unsigned*)(hb + (size_t)node * 128))[lane];
    float accx = di * di * bf_lo(sv);
    float accy = di * di * bf_hi(sv);
    int beg = rowptr[node], end = rowptr[node + 1];
    int i = beg;
    for (; i + 4 <= end; i += 4) {
        int2 e0 = sedge[i], e1 = sedge[i + 1], e2 = sedge[i + 2], e3 = sedge[i + 3];
        unsigned v0 = ((const unsigned*)(hb + (size_t)e0.x * 128))[lane];
        unsigned v1 = ((const unsigned*)(hb + (size_t)e1.x * 128))[lane];
        unsigned v2 = ((const unsigned*)(hb + (size_t)e2.x * 128))[lane];
        unsigned v3 = ((const unsigned*)(hb + (size_t)e3.x * 128))[lane];
        float w0 = __int_as_float(e0.y), w1 = __int_as_float(e1.y);
        float w2 = __int_as_float(e2.y), w3 = __int_as_float(e3.y);
        accx = fmaf(w0, bf_lo(v0), accx); accy = fmaf(w0, bf_hi(v0), accy);
        accx = fmaf(w1, bf_lo(v1), accx); accy = fmaf(w1, bf_hi(v1), accy);
        accx = fmaf(w2, bf_lo(v2), accx); accy = fmaf(w2, bf_hi(v2), accy);
        accx = fmaf(w3, bf_lo(v3), accx); accy = fmaf(w3, bf_hi(v3), accy);
    }
    for (; i < end; ++i) {
        int2 e = sedge[i];
        float w = __int_as_float(e.y);
        unsigned v = ((const unsigned*)(hb + (size_t)e.x * 128))[lane];
        accx = fmaf(w, bf_lo(v), accx);
        accy = fmaf(w, bf_hi(v), accy);
    }
    float2 bv = *((const float2*)bias + lane);
    float rx = fmaxf(accx + bv.x, 0.0f);
    float ry = fmaxf(accy + bv.y, 0.0f);
    BF8 p;
    p.h[0] = __float22bfloat162_rn(make_float2(rx, ry));
    ((unsigned*)(outb + (size_t)node * 128))[lane] = p.u.x;
}

// One wave per node, 64 bf16 channels (lane == channel). Writes f32 out+bias.
__global__ __launch_bounds__(256) void agg64_kernel(
    const int* __restrict__ rowptr, const int2* __restrict__ sedge,
    const unsigned short* __restrict__ hb, const float* __restrict__ dinv,
    const float* __restrict__ bias, float* __restrict__ out, int n) {
    int node = blockIdx.x * 4 + (threadIdx.x >> 6);
    if (node >= n) return;
    int lane = threadIdx.x & 63;
    float di = dinv[node];
    float acc = di * di * __uint_as_float((unsigned)hb[(size_t)node * 64 + lane] << 16);
    int beg = rowptr[node], end = rowptr[node + 1];
    int i = beg;
    for (; i + 4 <= end; i += 4) {
        int2 e0 = sedge[i], e1 = sedge[i + 1], e2 = sedge[i + 2], e3 = sedge[i + 3];
        float v0 = __uint_as_float((unsigned)hb[(size_t)e0.x * 64 + lane] << 16);
        float v1 = __uint_as_float((unsigned)hb[(size_t)e1.x * 64 + lane] << 16);
        float v2 = __uint_as_float((unsigned)hb[(size_t)e2.x * 64 + lane] << 16);
        float v3 = __uint_as_float((unsigned)hb[(size_t)e3.x * 64 + lane] << 16);
        acc = fmaf(__int_as_float(e0.y), v0, acc);
        acc = fmaf(__int_as_float(e1.y), v1, acc);
        acc = fmaf(__int_as_float(e2.y), v2, acc);
        acc = fmaf(__int_as_float(e3.y), v3, acc);
    }
    for (; i < end; ++i) {
        int2 e = sedge[i];
        float v = __uint_as_float((unsigned)hb[(size_t)e.x * 64 + lane] << 16);
        acc = fmaf(__int_as_float(e.y), v, acc);
    }
    out[(size_t)node * 64 + lane] = acc + bias[lane];
}

// ---------------------------------------------------------------------------
// MFMA bf16 GEMM (f32 A): C[M,N] = bf16(A[M,K] f32) @ bf16(B), C bf16.
// BT pre-transposed bf16 [N][K]. 4 waves/block, wave owns 16 rows x N.
// ---------------------------------------------------------------------------
template <int NT, int KS>
__global__ __launch_bounds__(256) void mfma_gemm_kernel(
    const float* __restrict__ A, const unsigned short* __restrict__ BT,
    unsigned short* __restrict__ C, int M) {
    constexpr int N = NT * 16;
    constexpr int K = KS * 32;
    const int tid = threadIdx.x;
    const int wave = tid >> 6, lane = tid & 63;
    const int quad = lane >> 4, m16 = lane & 15;
    const int rowBase = blockIdx.x * 64 + wave * 16;

    int rowA = rowBase + m16;
    if (rowA >= M) rowA = M - 1;
    const float* Arow = A + (size_t)rowA * K;
    const unsigned short* Bbase = BT + (size_t)m16 * K + quad * 8;

    f32x4 acc[NT];
#pragma unroll
    for (int nt = 0; nt < NT; nt++) acc[nt] = f32x4{0.f, 0.f, 0.f, 0.f};

#pragma unroll
    for (int ks = 0; ks < KS; ks++) {
        const int k0 = ks * 32 + quad * 8;
        f32x4 a0 = *(const f32x4*)(Arow + k0);
        f32x4 a1 = *(const f32x4*)(Arow + k0 + 4);
        BF8 af;
        af.h[0] = __float22bfloat162_rn(make_float2(a0.x, a0.y));
        af.h[1] = __float22bfloat162_rn(make_float2(a0.z, a0.w));
        af.h[2] = __float22bfloat162_rn(make_float2(a1.x, a1.y));
        af.h[3] = __float22bfloat162_rn(make_float2(a1.z, a1.w));
#pragma unroll
        for (int nt = 0; nt < NT; nt++) {
            BF8 bf;
            bf.u = *(const uint4*)(Bbase + (size_t)nt * 16 * K + ks * 32);
            acc[nt] = __builtin_amdgcn_mfma_f32_16x16x32_bf16(af.s, bf.s, acc[nt], 0, 0, 0);
        }
    }

#pragma unroll
    for (int nt = 0; nt < NT; nt++) {
#pragma unroll
        for (int r = 0; r < 4; r++) {
            int row = rowBase + quad * 4 + r;
            if (row < M)
                C[(size_t)row * N + nt * 16 + m16] = f32_to_bf16_rne(acc[nt][r]);
        }
    }
}

// Same but A is already bf16 (a1 stored relu'd bf16) — pure uint4 A-loads.
template <int NT, int KS>
__global__ __launch_bounds__(256) void mfma_gemm_bfA_kernel(
    const unsigned short* __restrict__ A, const unsigned short* __restrict__ BT,
    unsigned short* __restrict__ C, int M) {
    constexpr int N = NT * 16;
    constexpr int K = KS * 32;
    const int tid = threadIdx.x;
    const int wave = tid >> 6, lane = tid & 63;
    const int quad = lane >> 4, m16 = lane & 15;
    const int rowBase = blockIdx.x * 64 + wave * 16;

    int rowA = rowBase + m16;
    if (rowA >= M) rowA = M - 1;
    const unsigned short* Arow = A + (size_t)rowA * K;
    const unsigned short* Bbase = BT + (size_t)m16 * K + quad * 8;

    f32x4 acc[NT];
#pragma unroll
    for (int nt = 0; nt < NT; nt++) acc[nt] = f32x4{0.f, 0.f, 0.f, 0.f};

#pragma unroll
    for (int ks = 0; ks < KS; ks++) {
        const int k0 = ks * 32 + quad * 8;
        BF8 af;
        af.u = *(const uint4*)(Arow + k0);
#pragma unroll
        for (int nt = 0; nt < NT; nt++) {
            BF8 bf;
            bf.u = *(const uint4*)(Bbase + (size_t)nt * 16 * K + ks * 32);
            acc[nt] = __builtin_amdgcn_mfma_f32_16x16x32_bf16(af.s, bf.s, acc[nt], 0, 0, 0);
        }
    }

#pragma unroll
    for (int nt = 0; nt < NT; nt++) {
#pragma unroll
        for (int r = 0; r < 4; r++) {
            int row = rowBase + quad * 4 + r;
            if (row < M)
                C[(size_t)row * N + nt * 16 + m16] = f32_to_bf16_rne(acc[nt][r]);
        }
    }
}

extern "C" void kernel_launch(void* const* d_in, const int* in_sizes, int n_in,
                              void* d_out, int out_size, void* d_ws, size_t ws_size,
                              hipStream_t stream) {
    const float* x  = (const float*)d_in[0];
    const int*   ei = (const int*)d_in[1];   // [2, E] flat: src row then dst row
    const float* W1 = (const float*)d_in[2];
    const float* b1 = (const float*)d_in[3];
    const float* W2 = (const float*)d_in[4];
    const float* b2 = (const float*)d_in[5];
    float* out = (float*)d_out;

    const int IN_C = 256;
    const int N = in_sizes[0] / IN_C;
    const int E = in_sizes[1] / 2;
    const int* srcA = ei;
    const int* dstA = ei + E;

    char* ws = (char*)d_ws;
    const size_t KB = 1024, MB = 1024 * 1024;
    int*            counts = (int*)(ws);                    // N ints
    float*          dinv   = (float*)(ws + 256 * KB);       // N floats
    int*            rowptr = (int*)(ws + 512 * KB);         // N+1 ints
    int*            cursor = (int*)(ws + 768 * KB);         // N ints
    int*            bsums  = (int*)(ws + 992 * KB);         // ~64 ints
    unsigned short* w1t    = (unsigned short*)(ws + 1 * MB);           // 128x256 bf16
    unsigned short* w2t    = (unsigned short*)(ws + 1 * MB + 64 * KB); // 64x128 bf16
    int2*           sedge  = (int2*)(ws + 2 * MB);          // E int2 (6.4 MB)
    unsigned short* h1b    = (unsigned short*)(ws + 9 * MB);  // N*128 bf16 (12.8 MB)
    unsigned short* a1b    = (unsigned short*)(ws + 22 * MB); // N*128 bf16 (12.8 MB)
    unsigned short* h2b    = h1b;                           // reuse (N*64 bf16)

    const int nb256 = (N + 255) / 256;
    const int eb256 = (E + 255) / 256;
    const int nbScan = (N + 1 + 1023) / 1024;
    const int gGemm = (N + 63) / 64;

    // ---- CSR build + weight prep ----
    zero_int_kernel<<<nb256, 256, 0, stream>>>(counts, N);
    count_deg_kernel<<<eb256, 256, 0, stream>>>(dstA, counts, E);
    wtrans_kernel<<<(256 * 128 + 128 * 64 + 255) / 256, 256, 0, stream>>>(W1, W2, w1t, w2t);
    scan_partial_kernel<<<nbScan, 256, 0, stream>>>(counts, bsums, dinv, N);
    scan_bsums_kernel<<<1, 64, 0, stream>>>(bsums, nbScan);
    scan_final_kernel<<<nbScan, 256, 0, stream>>>(counts, bsums, rowptr, cursor, N);
    fill_kernel<<<eb256, 256, 0, stream>>>(srcA, dstA, dinv, cursor, sedge, E);

    // ---- layer 1: h1 = bf16(x) @ bf16(W1) ; a1 = bf16(relu(agg + b1)) ----
    mfma_gemm_kernel<8, 8><<<gGemm, 256, 0, stream>>>(x, w1t, h1b, N);
    agg128_kernel<<<(N + 3) / 4, 256, 0, stream>>>(rowptr, sedge, h1b, dinv, b1, a1b, N);

    // ---- layer 2: h2 = a1 @ bf16(W2) ; out = agg + b2 (f32) ----
    mfma_gemm_bfA_kernel<4, 4><<<gGemm, 256, 0, stream>>>(a1b, w2t, h2b, N);
    agg64_kernel<<<(N + 3) / 4, 256, 0, stream>>>(rowptr, sedge, h2b, dinv, b2, out, N);
}

// Round 7
// 281.541 us; speedup vs baseline: 3.7395x; 1.0639x over previous
//
#include <hip/hip_runtime.h>
#include <hip/hip_bf16.h>

// ---------------------------------------------------------------------------
// 2-layer GCN forward on MI355X — round 7.
// R6 post-mortem: gemm1 44 µs (latency-bound, 3 waves/SIMD, fetch at 850 GB/s)
// and fill 45 µs (scattered 8B stores -> 53 MB of partial-line writebacks).
// Changes: (1) GEMM blocks cover 32 rows, waves split rows x cols -> 2x waves.
// (2) fill replaced by 2-phase bucket sort (coarse dst>>8 scatter into tmp,
//     then per-bucket L2-local finalize) — write-combining friendly.
// (3) agg kernels batch 8 edges for deeper MLP.
// ---------------------------------------------------------------------------

typedef __attribute__((ext_vector_type(8))) short short8;
typedef __attribute__((ext_vector_type(4))) float f32x4;

union BF8 {
    short8 s;
    uint4 u;
    __hip_bfloat162 h[4];
};

__device__ __forceinline__ unsigned short f32_to_bf16_rne(float f) {
    unsigned u = __float_as_uint(f);
    return (unsigned short)((u + 0x7fffu + ((u >> 16) & 1u)) >> 16);
}
__device__ __forceinline__ float bf_lo(unsigned v) { return __uint_as_float(v << 16); }
__device__ __forceinline__ float bf_hi(unsigned v) { return __uint_as_float(v & 0xffff0000u); }

__global__ void zero_int_kernel(int* __restrict__ p, int n) {
    int i = blockIdx.x * blockDim.x + threadIdx.x;
    if (i < n) p[i] = 0;
}

__global__ void count_deg_kernel(const int* __restrict__ dst, int* __restrict__ counts, int e) {
    int i = blockIdx.x * blockDim.x + threadIdx.x;
    if (i < e) atomicAdd(&counts[dst[i]], 1);
}

// Transpose+convert both weights in one launch.
__global__ void wtrans_kernel(const float* __restrict__ W1, const float* __restrict__ W2,
                              unsigned short* __restrict__ w1t, unsigned short* __restrict__ w2t) {
    int i = blockIdx.x * blockDim.x + threadIdx.x;
    if (i < 256 * 128) {
        int k = i / 128, n = i % 128;
        w1t[n * 256 + k] = f32_to_bf16_rne(W1[i]);
    } else {
        int j = i - 256 * 128;
        if (j < 128 * 64) {
            int k = j / 64, n = j % 64;
            w2t[n * 128 + k] = f32_to_bf16_rne(W2[j]);
        }
    }
}

// ---- Hierarchical exclusive scan over counts[0..n) -> rowptr[0..n] ----
__global__ __launch_bounds__(256) void scan_partial_kernel(const int* __restrict__ counts,
                                                           int* __restrict__ bsums,
                                                           float* __restrict__ dinv, int n) {
    __shared__ int wsum[4];
    const int tid = threadIdx.x;
    const int lane = tid & 63, wv = tid >> 6;
    int base = blockIdx.x * 1024 + tid * 4;
    int s = 0;
#pragma unroll
    for (int j = 0; j < 4; j++) {
        int i = base + j;
        if (i < n) {
            int c = counts[i];
            s += c;
            dinv[i] = rsqrtf((float)c + 1.0f);
        }
    }
#pragma unroll
    for (int off = 1; off < 64; off <<= 1) {
        int y = __shfl_up(s, off, 64);
        if (lane >= off) s += y;
    }
    if (lane == 63) wsum[wv] = s;
    __syncthreads();
    if (tid == 0) bsums[blockIdx.x] = wsum[0] + wsum[1] + wsum[2] + wsum[3];
}

__global__ void scan_bsums_kernel(int* __restrict__ bsums, int nb) {
    int lane = threadIdx.x;
    int carry = 0;
    for (int base = 0; base < nb; base += 64) {
        int i = base + lane;
        int v = (i < nb) ? bsums[i] : 0;
        int x = v;
#pragma unroll
        for (int off = 1; off < 64; off <<= 1) {
            int y = __shfl_up(x, off, 64);
            if (lane >= off) x += y;
        }
        if (i < nb) bsums[i] = carry + x - v;  // exclusive
        carry += __shfl(x, 63, 64);
    }
}

__global__ __launch_bounds__(256) void scan_final_kernel(const int* __restrict__ counts,
                                                         const int* __restrict__ bsums,
                                                         int* __restrict__ rowptr, int n) {
    __shared__ int wsum[4];
    const int tid = threadIdx.x;
    const int lane = tid & 63, wv = tid >> 6;
    int base = blockIdx.x * 1024 + tid * 4;
    int v[4];
#pragma unroll
    for (int j = 0; j < 4; j++) {
        int i = base + j;
        v[j] = (i < n) ? counts[i] : 0;
    }
    int tot = v[0] + v[1] + v[2] + v[3];
    int x = tot;
#pragma unroll
    for (int off = 1; off < 64; off <<= 1) {
        int y = __shfl_up(x, off, 64);
        if (lane >= off) x += y;
    }
    if (lane == 63) wsum[wv] = x;
    __syncthreads();
    int wpre = 0;
    for (int k = 0; k < wv; k++) wpre += wsum[k];
    int pre = bsums[blockIdx.x] + wpre + (x - tot);
#pragma unroll
    for (int j = 0; j < 4; j++) {
        int i = base + j;
        if (i <= n) rowptr[i] = pre;
        pre += v[j];
    }
}

// bcursor[b] = rowptr[b*256]  (start of bucket b's CSR region)
__global__ void init_bcursor_kernel(const int* __restrict__ rowptr, int* __restrict__ bcursor,
                                    int nb) {
    int b = blockIdx.x * blockDim.x + threadIdx.x;
    if (b < nb) bcursor[b] = rowptr[b * 256];
}

// ---- Phase A: coarse scatter of (src,dst) into tmp, bucketed by dst>>8 ----
// Per-block LDS histogram + one chunk reservation per (block,bucket) keeps
// same-bucket records consecutive -> near-full-line writebacks.
#define ACHUNK 2048
__global__ __launch_bounds__(256) void bucketA_kernel(const int* __restrict__ src,
                                                      const int* __restrict__ dst,
                                                      int* __restrict__ bcursor,
                                                      int2* __restrict__ tmp, int e, int nb) {
    __shared__ int sdst[ACHUNK];
    __shared__ int hist[256];   // nb <= 256
    const int tid = threadIdx.x;
    const int start = blockIdx.x * ACHUNK;
    const int cnt = min(ACHUNK, e - start);
    if (tid < nb) hist[tid] = 0;
    __syncthreads();
    for (int i = tid; i < cnt; i += 256) {
        int d = dst[start + i];
        sdst[i] = d;
        atomicAdd(&hist[d >> 8], 1);
    }
    __syncthreads();
    // reserve a contiguous chunk per bucket; hist becomes the running cursor
    if (tid < nb) {
        int h = hist[tid];
        hist[tid] = (h > 0) ? atomicAdd(&bcursor[tid], h) : 0;
    }
    __syncthreads();
    for (int i = tid; i < cnt; i += 256) {
        int d = sdst[i];
        int slot = atomicAdd(&hist[d >> 8], 1);
        tmp[slot] = make_int2(src[start + i], d);
    }
}

// ---- Phase B: one block per bucket; finalize CSR records (src, weight) ----
// Reads its tmp region sequentially, scatters into its own <=32 KB CSR region
// (L2-local, lines fill completely).
__global__ __launch_bounds__(256) void bucketB_kernel(const int* __restrict__ rowptr,
                                                      const int2* __restrict__ tmp,
                                                      const float* __restrict__ dinv,
                                                      int2* __restrict__ sedge, int n) {
    __shared__ int lcur[256];
    __shared__ float ldinv[256];
    const int tid = threadIdx.x;
    const int nodeBase = blockIdx.x * 256;
    const int nNodes = min(256, n - nodeBase);
    if (tid < nNodes) {
        lcur[tid] = rowptr[nodeBase + tid];
        ldinv[tid] = dinv[nodeBase + tid];
    }
    __syncthreads();
    const int beg = rowptr[nodeBase];
    const int end = rowptr[nodeBase + nNodes];
    for (int i = beg + tid; i < end; i += 256) {
        int2 r = tmp[i];
        int j = r.y - nodeBase;
        float w = dinv[r.x] * ldinv[j];
        int pos = atomicAdd(&lcur[j], 1);
        sedge[pos] = make_int2(r.x, __float_as_int(w));
    }
}

// One wave per node, 128 bf16 channels (uint/lane = 2 channels).
// Writes a1 = bf16(relu(bias + dinv^2*h_self + sum w*h_src)).
__global__ __launch_bounds__(256) void agg128_kernel(
    const int* __restrict__ rowptr, const int2* __restrict__ sedge,
    const unsigned short* __restrict__ hb, const float* __restrict__ dinv,
    const float* __restrict__ bias, unsigned short* __restrict__ outb, int n) {
    int node = blockIdx.x * 4 + (threadIdx.x >> 6);
    if (node >= n) return;
    int lane = threadIdx.x & 63;
    float di = dinv[node];
    unsigned sv = ((const unsigned*)(hb + (size_t)node * 128))[lane];
    float accx = di * di * bf_lo(sv);
    float accy = di * di * bf_hi(sv);
    int beg = rowptr[node], end = rowptr[node + 1];
    int i = beg;
    for (; i + 8 <= end; i += 8) {
        int2 e[8];
        unsigned v[8];
#pragma unroll
        for (int j = 0; j < 8; j++) e[j] = sedge[i + j];
#pragma unroll
        for (int j = 0; j < 8; j++)
            v[j] = ((const unsigned*)(hb + (size_t)e[j].x * 128))[lane];
#pragma unroll
        for (int j = 0; j < 8; j++) {
            float w = __int_as_float(e[j].y);
            accx = fmaf(w, bf_lo(v[j]), accx);
            accy = fmaf(w, bf_hi(v[j]), accy);
        }
    }
    for (; i + 4 <= end; i += 4) {
        int2 e[4];
        unsigned v[4];
#pragma unroll
        for (int j = 0; j < 4; j++) e[j] = sedge[i + j];
#pragma unroll
        for (int j = 0; j < 4; j++)
            v[j] = ((const unsigned*)(hb + (size_t)e[j].x * 128))[lane];
#pragma unroll
        for (int j = 0; j < 4; j++) {
            float w = __int_as_float(e[j].y);
            accx = fmaf(w, bf_lo(v[j]), accx);
            accy = fmaf(w, bf_hi(v[j]), accy);
        }
    }
    for (; i < end; ++i) {
        int2 e = sedge[i];
        float w = __int_as_float(e.y);
        unsigned v = ((const unsigned*)(hb + (size_t)e.x * 128))[lane];
        accx = fmaf(w, bf_lo(v), accx);
        accy = fmaf(w, bf_hi(v), accy);
    }
    float2 bv = *((const float2*)bias + lane);
    float rx = fmaxf(accx + bv.x, 0.0f);
    float ry = fmaxf(accy + bv.y, 0.0f);
    BF8 p;
    p.h[0] = __float22bfloat162_rn(make_float2(rx, ry));
    ((unsigned*)(outb + (size_t)node * 128))[lane] = p.u.x;
}

// One wave per node, 64 bf16 channels (lane == channel). Writes f32 out+bias.
__global__ __launch_bounds__(256) void agg64_kernel(
    const int* __restrict__ rowptr, const int2* __restrict__ sedge,
    const unsigned short* __restrict__ hb, const float* __restrict__ dinv,
    const float* __restrict__ bias, float* __restrict__ out, int n) {
    int node = blockIdx.x * 4 + (threadIdx.x >> 6);
    if (node >= n) return;
    int lane = threadIdx.x & 63;
    float di = dinv[node];
    float acc = di * di * __uint_as_float((unsigned)hb[(size_t)node * 64 + lane] << 16);
    int beg = rowptr[node], end = rowptr[node + 1];
    int i = beg;
    for (; i + 8 <= end; i += 8) {
        int2 e[8];
        float v[8];
#pragma unroll
        for (int j = 0; j < 8; j++) e[j] = sedge[i + j];
#pragma unroll
        for (int j = 0; j < 8; j++)
            v[j] = __uint_as_float((unsigned)hb[(size_t)e[j].x * 64 + lane] << 16);
#pragma unroll
        for (int j = 0; j < 8; j++) acc = fmaf(__int_as_float(e[j].y), v[j], acc);
    }
    for (; i + 4 <= end; i += 4) {
        int2 e[4];
        float v[4];
#pragma unroll
        for (int j = 0; j < 4; j++) e[j] = sedge[i + j];
#pragma unroll
        for (int j = 0; j < 4; j++)
            v[j] = __uint_as_float((unsigned)hb[(size_t)e[j].x * 64 + lane] << 16);
#pragma unroll
        for (int j = 0; j < 4; j++) acc = fmaf(__int_as_float(e[j].y), v[j], acc);
    }
    for (; i < end; ++i) {
        int2 e = sedge[i];
        float v = __uint_as_float((unsigned)hb[(size_t)e.x * 64 + lane] << 16);
        acc = fmaf(__int_as_float(e.y), v, acc);
    }
    out[(size_t)node * 64 + lane] = acc + bias[lane];
}

// ---------------------------------------------------------------------------
// MFMA bf16 GEMM. Block covers 32 rows x NCOL cols; 4 waves split as
// 2 row-halves x 2 col-halves (2x wave count vs R6 for latency hiding).
// BFA=false: A is f32 (cvt in regs). BFA=true: A is bf16.
// ---------------------------------------------------------------------------
template <int NT, int KS, bool BFA>
__global__ __launch_bounds__(256) void mfma_gemm_kernel(
    const void* __restrict__ Av, const unsigned short* __restrict__ BT,
    unsigned short* __restrict__ C, int M) {
    constexpr int NCOL = NT * 32;
    constexpr int K = KS * 32;
    const int tid = threadIdx.x;
    const int wave = tid >> 6, lane = tid & 63;
    const int quad = lane >> 4, m16 = lane & 15;
    const int rw = wave & 1, cw = wave >> 1;
    const int rowBase = blockIdx.x * 32 + rw * 16;
    const int colBase = cw * NT * 16;

    int rowA = rowBase + m16;
    if (rowA >= M) rowA = M - 1;
    const float* ArowF = (const float*)Av + (size_t)rowA * K;
    const unsigned short* ArowB = (const unsigned short*)Av + (size_t)rowA * K;
    const unsigned short* Bb0 = BT + (size_t)(colBase + m16) * K + quad * 8;

    f32x4 acc[NT];
#pragma unroll
    for (int nt = 0; nt < NT; nt++) acc[nt] = f32x4{0.f, 0.f, 0.f, 0.f};

#pragma unroll
    for (int ks = 0; ks < KS; ks++) {
        const int k0 = ks * 32 + quad * 8;
        BF8 af;
        if constexpr (BFA) {
            af.u = *(const uint4*)(ArowB + k0);
        } else {
            f32x4 a0 = *(const f32x4*)(ArowF + k0);
            f32x4 a1 = *(const f32x4*)(ArowF + k0 + 4);
            af.h[0] = __float22bfloat162_rn(make_float2(a0.x, a0.y));
            af.h[1] = __float22bfloat162_rn(make_float2(a0.z, a0.w));
            af.h[2] = __float22bfloat162_rn(make_float2(a1.x, a1.y));
            af.h[3] = __float22bfloat162_rn(make_float2(a1.z, a1.w));
        }
#pragma unroll
        for (int nt = 0; nt < NT; nt++) {
            BF8 bf;
            bf.u = *(const uint4*)(Bb0 + (size_t)nt * 16 * K + ks * 32);
            acc[nt] = __builtin_amdgcn_mfma_f32_16x16x32_bf16(af.s, bf.s, acc[nt], 0, 0, 0);
        }
    }

#pragma unroll
    for (int nt = 0; nt < NT; nt++) {
#pragma unroll
        for (int r = 0; r < 4; r++) {
            int row = rowBase + quad * 4 + r;
            if (row < M)
                C[(size_t)row * NCOL + colBase + nt * 16 + m16] = f32_to_bf16_rne(acc[nt][r]);
        }
    }
}

extern "C" void kernel_launch(void* const* d_in, const int* in_sizes, int n_in,
                              void* d_out, int out_size, void* d_ws, size_t ws_size,
                              hipStream_t stream) {
    const float* x  = (const float*)d_in[0];
    const int*   ei = (const int*)d_in[1];   // [2, E] flat: src row then dst row
    const float* W1 = (const float*)d_in[2];
    const float* b1 = (const float*)d_in[3];
    const float* W2 = (const float*)d_in[4];
    const float* b2 = (const float*)d_in[5];
    float* out = (float*)d_out;

    const int IN_C = 256;
    const int N = in_sizes[0] / IN_C;
    const int E = in_sizes[1] / 2;
    const int* srcA = ei;
    const int* dstA = ei + E;

    char* ws = (char*)d_ws;
    const size_t KB = 1024, MB = 1024 * 1024;
    int*            counts  = (int*)(ws);                    // N ints
    float*          dinv    = (float*)(ws + 256 * KB);       // N floats
    int*            rowptr  = (int*)(ws + 512 * KB);         // N+1 ints
    int*            bcursor = (int*)(ws + 768 * KB);         // <=256 ints
    int*            bsums   = (int*)(ws + 992 * KB);         // ~64 ints
    unsigned short* w1t     = (unsigned short*)(ws + 1 * MB);           // 128x256 bf16
    unsigned short* w2t     = (unsigned short*)(ws + 1 * MB + 64 * KB); // 64x128 bf16
    int2*           sedge   = (int2*)(ws + 2 * MB);          // E int2 (6.4 MB)
    int2*           tmp     = (int2*)(ws + 9 * MB);          // E int2 (6.4 MB)
    unsigned short* h1b     = (unsigned short*)(ws + 16 * MB); // N*128 bf16 (12.8 MB)
    unsigned short* a1b     = (unsigned short*)(ws + 29 * MB); // N*128 bf16 (12.8 MB)
    unsigned short* h2b     = h1b;                           // reuse (N*64 bf16)

    const int nb256 = (N + 255) / 256;
    const int eb256 = (E + 255) / 256;
    const int nbScan = (N + 1 + 1023) / 1024;
    const int NB = (N + 255) / 256;           // coarse buckets (<=256)
    const int gGemm = (N + 31) / 32;

    // ---- CSR build + weight prep ----
    zero_int_kernel<<<nb256, 256, 0, stream>>>(counts, N);
    count_deg_kernel<<<eb256, 256, 0, stream>>>(dstA, counts, E);
    wtrans_kernel<<<(256 * 128 + 128 * 64 + 255) / 256, 256, 0, stream>>>(W1, W2, w1t, w2t);
    scan_partial_kernel<<<nbScan, 256, 0, stream>>>(counts, bsums, dinv, N);
    scan_bsums_kernel<<<1, 64, 0, stream>>>(bsums, nbScan);
    scan_final_kernel<<<nbScan, 256, 0, stream>>>(counts, bsums, rowptr, N);
    init_bcursor_kernel<<<(NB + 255) / 256, 256, 0, stream>>>(rowptr, bcursor, NB);
    bucketA_kernel<<<(E + ACHUNK - 1) / ACHUNK, 256, 0, stream>>>(srcA, dstA, bcursor, tmp, E, NB);
    bucketB_kernel<<<NB, 256, 0, stream>>>(rowptr, tmp, dinv, sedge, N);

    // ---- layer 1: h1 = bf16(x) @ bf16(W1) ; a1 = bf16(relu(agg + b1)) ----
    mfma_gemm_kernel<4, 8, false><<<gGemm, 256, 0, stream>>>(x, w1t, h1b, N);
    agg128_kernel<<<(N + 3) / 4, 256, 0, stream>>>(rowptr, sedge, h1b, dinv, b1, a1b, N);

    // ---- layer 2: h2 = a1 @ bf16(W2) ; out = agg + b2 (f32) ----
    mfma_gemm_kernel<2, 4, true><<<gGemm, 256, 0, stream>>>(a1b, w2t, h2b, N);
    agg64_kernel<<<(N + 3) / 4, 256, 0, stream>>>(rowptr, sedge, h2b, dinv, b2, out, N);
}

// Round 8
// 279.167 us; speedup vs baseline: 3.7713x; 1.0085x over previous
//
#include <hip/hip_runtime.h>
#include <hip/hip_bf16.h>

// ---------------------------------------------------------------------------
// 2-layer GCN forward on MI355X — round 8.
// R7 post-mortem: gemm1 unchanged at 47 µs despite 2x waves -> not MLP-bound;
// the A-fragment global load touches 16 cache lines/instr (rows 1KB apart).
// Fix: stage A tile via fully-coalesced global loads into a pad-swizzled
// fragment-ready bf16 LDS layout (row stride K+16 -> <=4-way bank alias);
// one ds_read_b128 per A-fragment. B stays direct (L1/L2-resident weights).
// ---------------------------------------------------------------------------

typedef __attribute__((ext_vector_type(8))) short short8;
typedef __attribute__((ext_vector_type(4))) float f32x4;

union BF8 {
    short8 s;
    uint4 u;
    __hip_bfloat162 h[4];
};

__device__ __forceinline__ unsigned short f32_to_bf16_rne(float f) {
    unsigned u = __float_as_uint(f);
    return (unsigned short)((u + 0x7fffu + ((u >> 16) & 1u)) >> 16);
}
__device__ __forceinline__ float bf_lo(unsigned v) { return __uint_as_float(v << 16); }
__device__ __forceinline__ float bf_hi(unsigned v) { return __uint_as_float(v & 0xffff0000u); }

__global__ void zero_int_kernel(int* __restrict__ p, int n) {
    int i = blockIdx.x * blockDim.x + threadIdx.x;
    if (i < n) p[i] = 0;
}

__global__ void count_deg_kernel(const int* __restrict__ dst, int* __restrict__ counts, int e) {
    int i = blockIdx.x * blockDim.x + threadIdx.x;
    if (i < e) atomicAdd(&counts[dst[i]], 1);
}

// Transpose+convert both weights in one launch.
__global__ void wtrans_kernel(const float* __restrict__ W1, const float* __restrict__ W2,
                              unsigned short* __restrict__ w1t, unsigned short* __restrict__ w2t) {
    int i = blockIdx.x * blockDim.x + threadIdx.x;
    if (i < 256 * 128) {
        int k = i / 128, n = i % 128;
        w1t[n * 256 + k] = f32_to_bf16_rne(W1[i]);
    } else {
        int j = i - 256 * 128;
        if (j < 128 * 64) {
            int k = j / 64, n = j % 64;
            w2t[n * 128 + k] = f32_to_bf16_rne(W2[j]);
        }
    }
}

// ---- Hierarchical exclusive scan over counts[0..n) -> rowptr[0..n] ----
__global__ __launch_bounds__(256) void scan_partial_kernel(const int* __restrict__ counts,
                                                           int* __restrict__ bsums,
                                                           float* __restrict__ dinv, int n) {
    __shared__ int wsum[4];
    const int tid = threadIdx.x;
    const int lane = tid & 63, wv = tid >> 6;
    int base = blockIdx.x * 1024 + tid * 4;
    int s = 0;
#pragma unroll
    for (int j = 0; j < 4; j++) {
        int i = base + j;
        if (i < n) {
            int c = counts[i];
            s += c;
            dinv[i] = rsqrtf((float)c + 1.0f);
        }
    }
#pragma unroll
    for (int off = 1; off < 64; off <<= 1) {
        int y = __shfl_up(s, off, 64);
        if (lane >= off) s += y;
    }
    if (lane == 63) wsum[wv] = s;
    __syncthreads();
    if (tid == 0) bsums[blockIdx.x] = wsum[0] + wsum[1] + wsum[2] + wsum[3];
}

__global__ void scan_bsums_kernel(int* __restrict__ bsums, int nb) {
    int lane = threadIdx.x;
    int carry = 0;
    for (int base = 0; base < nb; base += 64) {
        int i = base + lane;
        int v = (i < nb) ? bsums[i] : 0;
        int x = v;
#pragma unroll
        for (int off = 1; off < 64; off <<= 1) {
            int y = __shfl_up(x, off, 64);
            if (lane >= off) x += y;
        }
        if (i < nb) bsums[i] = carry + x - v;  // exclusive
        carry += __shfl(x, 63, 64);
    }
}

__global__ __launch_bounds__(256) void scan_final_kernel(const int* __restrict__ counts,
                                                         const int* __restrict__ bsums,
                                                         int* __restrict__ rowptr, int n) {
    __shared__ int wsum[4];
    const int tid = threadIdx.x;
    const int lane = tid & 63, wv = tid >> 6;
    int base = blockIdx.x * 1024 + tid * 4;
    int v[4];
#pragma unroll
    for (int j = 0; j < 4; j++) {
        int i = base + j;
        v[j] = (i < n) ? counts[i] : 0;
    }
    int tot = v[0] + v[1] + v[2] + v[3];
    int x = tot;
#pragma unroll
    for (int off = 1; off < 64; off <<= 1) {
        int y = __shfl_up(x, off, 64);
        if (lane >= off) x += y;
    }
    if (lane == 63) wsum[wv] = x;
    __syncthreads();
    int wpre = 0;
    for (int k = 0; k < wv; k++) wpre += wsum[k];
    int pre = bsums[blockIdx.x] + wpre + (x - tot);
#pragma unroll
    for (int j = 0; j < 4; j++) {
        int i = base + j;
        if (i <= n) rowptr[i] = pre;
        pre += v[j];
    }
}

// bcursor[b] = rowptr[b*256]
__global__ void init_bcursor_kernel(const int* __restrict__ rowptr, int* __restrict__ bcursor,
                                    int nb) {
    int b = blockIdx.x * blockDim.x + threadIdx.x;
    if (b < nb) bcursor[b] = rowptr[b * 256];
}

// ---- Phase A: coarse scatter of (src,dst) into tmp, bucketed by dst>>8 ----
#define ACHUNK 2048
__global__ __launch_bounds__(256) void bucketA_kernel(const int* __restrict__ src,
                                                      const int* __restrict__ dst,
                                                      int* __restrict__ bcursor,
                                                      int2* __restrict__ tmp, int e, int nb) {
    __shared__ int sdst[ACHUNK];
    __shared__ int hist[256];   // nb <= 256
    const int tid = threadIdx.x;
    const int start = blockIdx.x * ACHUNK;
    const int cnt = min(ACHUNK, e - start);
    if (tid < nb) hist[tid] = 0;
    __syncthreads();
    for (int i = tid; i < cnt; i += 256) {
        int d = dst[start + i];
        sdst[i] = d;
        atomicAdd(&hist[d >> 8], 1);
    }
    __syncthreads();
    if (tid < nb) {
        int h = hist[tid];
        hist[tid] = (h > 0) ? atomicAdd(&bcursor[tid], h) : 0;
    }
    __syncthreads();
    for (int i = tid; i < cnt; i += 256) {
        int d = sdst[i];
        int slot = atomicAdd(&hist[d >> 8], 1);
        tmp[slot] = make_int2(src[start + i], d);
    }
}

// ---- Phase B: one block per bucket; finalize CSR records (src, weight) ----
__global__ __launch_bounds__(256) void bucketB_kernel(const int* __restrict__ rowptr,
                                                      const int2* __restrict__ tmp,
                                                      const float* __restrict__ dinv,
                                                      int2* __restrict__ sedge, int n) {
    __shared__ int lcur[256];
    __shared__ float ldinv[256];
    const int tid = threadIdx.x;
    const int nodeBase = blockIdx.x * 256;
    const int nNodes = min(256, n - nodeBase);
    if (tid < nNodes) {
        lcur[tid] = rowptr[nodeBase + tid];
        ldinv[tid] = dinv[nodeBase + tid];
    }
    __syncthreads();
    const int beg = rowptr[nodeBase];
    const int end = rowptr[nodeBase + nNodes];
    for (int i = beg + tid; i < end; i += 256) {
        int2 r = tmp[i];
        int j = r.y - nodeBase;
        float w = dinv[r.x] * ldinv[j];
        int pos = atomicAdd(&lcur[j], 1);
        sedge[pos] = make_int2(r.x, __float_as_int(w));
    }
}

// One wave per node, 128 bf16 channels. Writes a1 = bf16(relu(bias + agg)).
__global__ __launch_bounds__(256) void agg128_kernel(
    const int* __restrict__ rowptr, const int2* __restrict__ sedge,
    const unsigned short* __restrict__ hb, const float* __restrict__ dinv,
    const float* __restrict__ bias, unsigned short* __restrict__ outb, int n) {
    int node = blockIdx.x * 4 + (threadIdx.x >> 6);
    if (node >= n) return;
    int lane = threadIdx.x & 63;
    float di = dinv[node];
    unsigned sv = ((const unsigned*)(hb + (size_t)node * 128))[lane];
    float accx = di * di * bf_lo(sv);
    float accy = di * di * bf_hi(sv);
    int beg = rowptr[node], end = rowptr[node + 1];
    int i = beg;
    for (; i + 8 <= end; i += 8) {
        int2 e[8];
        unsigned v[8];
#pragma unroll
        for (int j = 0; j < 8; j++) e[j] = sedge[i + j];
#pragma unroll
        for (int j = 0; j < 8; j++)
            v[j] = ((const unsigned*)(hb + (size_t)e[j].x * 128))[lane];
#pragma unroll
        for (int j = 0; j < 8; j++) {
            float w = __int_as_float(e[j].y);
            accx = fmaf(w, bf_lo(v[j]), accx);
            accy = fmaf(w, bf_hi(v[j]), accy);
        }
    }
    for (; i + 4 <= end; i += 4) {
        int2 e[4];
        unsigned v[4];
#pragma unroll
        for (int j = 0; j < 4; j++) e[j] = sedge[i + j];
#pragma unroll
        for (int j = 0; j < 4; j++)
            v[j] = ((const unsigned*)(hb + (size_t)e[j].x * 128))[lane];
#pragma unroll
        for (int j = 0; j < 4; j++) {
            float w = __int_as_float(e[j].y);
            accx = fmaf(w, bf_lo(v[j]), accx);
            accy = fmaf(w, bf_hi(v[j]), accy);
        }
    }
    for (; i < end; ++i) {
        int2 e = sedge[i];
        float w = __int_as_float(e.y);
        unsigned v = ((const unsigned*)(hb + (size_t)e.x * 128))[lane];
        accx = fmaf(w, bf_lo(v), accx);
        accy = fmaf(w, bf_hi(v), accy);
    }
    float2 bv = *((const float2*)bias + lane);
    float rx = fmaxf(accx + bv.x, 0.0f);
    float ry = fmaxf(accy + bv.y, 0.0f);
    BF8 p;
    p.h[0] = __float22bfloat162_rn(make_float2(rx, ry));
    ((unsigned*)(outb + (size_t)node * 128))[lane] = p.u.x;
}

// One wave per node, 64 bf16 channels. Writes f32 out+bias.
__global__ __launch_bounds__(256) void agg64_kernel(
    const int* __restrict__ rowptr, const int2* __restrict__ sedge,
    const unsigned short* __restrict__ hb, const float* __restrict__ dinv,
    const float* __restrict__ bias, float* __restrict__ out, int n) {
    int node = blockIdx.x * 4 + (threadIdx.x >> 6);
    if (node >= n) return;
    int lane = threadIdx.x & 63;
    float di = dinv[node];
    float acc = di * di * __uint_as_float((unsigned)hb[(size_t)node * 64 + lane] << 16);
    int beg = rowptr[node], end = rowptr[node + 1];
    int i = beg;
    for (; i + 8 <= end; i += 8) {
        int2 e[8];
        float v[8];
#pragma unroll
        for (int j = 0; j < 8; j++) e[j] = sedge[i + j];
#pragma unroll
        for (int j = 0; j < 8; j++)
            v[j] = __uint_as_float((unsigned)hb[(size_t)e[j].x * 64 + lane] << 16);
#pragma unroll
        for (int j = 0; j < 8; j++) acc = fmaf(__int_as_float(e[j].y), v[j], acc);
    }
    for (; i + 4 <= end; i += 4) {
        int2 e[4];
        float v[4];
#pragma unroll
        for (int j = 0; j < 4; j++) e[j] = sedge[i + j];
#pragma unroll
        for (int j = 0; j < 4; j++)
            v[j] = __uint_as_float((unsigned)hb[(size_t)e[j].x * 64 + lane] << 16);
#pragma unroll
        for (int j = 0; j < 4; j++) acc = fmaf(__int_as_float(e[j].y), v[j], acc);
    }
    for (; i < end; ++i) {
        int2 e = sedge[i];
        float v = __uint_as_float((unsigned)hb[(size_t)e.x * 64 + lane] << 16);
        acc = fmaf(__int_as_float(e.y), v, acc);
    }
    out[(size_t)node * 64 + lane] = acc + bias[lane];
}

// ---------------------------------------------------------------------------
// MFMA bf16 GEMM with coalesced LDS staging of A.
// Block = 256 thr (4 waves), 64 rows x NCOL (= NT*16) cols; wave w owns rows
// [w*16, w*16+16). A staged as bf16 LDS [64][K+16] (pad -> word-stride 8 mod
// 32 -> <=4-way bank alias); fragment = one ds_read_b128. B direct (cached).
// BFA=false: A f32 (cvt during staging); BFA=true: A bf16.
// ---------------------------------------------------------------------------
template <int NT, int KS, bool BFA>
__global__ __launch_bounds__(256) void mfma_gemm_kernel(
    const void* __restrict__ Av, const unsigned short* __restrict__ BT,
    unsigned short* __restrict__ C, int M) {
    constexpr int NCOL = NT * 16;
    constexpr int K = KS * 32;
    constexpr int LSTRIDE = K + 16;            // elements; byte stride mult of 16
    __shared__ unsigned short Alds[64 * LSTRIDE];

    const int tid = threadIdx.x;
    const int wave = tid >> 6, lane = tid & 63;
    const int quad = lane >> 4, m16 = lane & 15;
    const int rowBase = blockIdx.x * 64;

    // ---- stage A (coalesced: thread t reads 16B at tile_base + t*16) ----
    if constexpr (BFA) {
        const unsigned short* Ab = (const unsigned short*)Av;
        constexpr int ITERS = K / 32;          // 64*K bf16 / (256 thr * 8 elem)
#pragma unroll
        for (int it = 0; it < ITERS; it++) {
            int p = it * 2048 + tid * 8;       // bf16 index in 64 x K tile
            int row = p / K, col = p % K;
            int rg = rowBase + row;
            if (rg >= M) rg = M - 1;
            uint4 v = *(const uint4*)(Ab + (size_t)rg * K + col);
            *(uint4*)&Alds[row * LSTRIDE + col] = v;
        }
    } else {
        const float* Af = (const float*)Av;
        constexpr int ITERS = K / 16;          // 64*K f32 / (256 thr * 4 elem)
#pragma unroll
        for (int it = 0; it < ITERS; it++) {
            int p = it * 1024 + tid * 4;       // f32 index in 64 x K tile
            int row = p / K, col = p % K;
            int rg = rowBase + row;
            if (rg >= M) rg = M - 1;
            f32x4 v = *(const f32x4*)(Af + (size_t)rg * K + col);
            BF8 cv;
            cv.h[0] = __float22bfloat162_rn(make_float2(v.x, v.y));
            cv.h[1] = __float22bfloat162_rn(make_float2(v.z, v.w));
            *(uint2*)&Alds[row * LSTRIDE + col] = make_uint2(cv.u.x, cv.u.y);
        }
    }
    __syncthreads();

    const unsigned short* Bb0 = BT + (size_t)m16 * K + quad * 8;
    const unsigned short* Afrag0 = &Alds[(wave * 16 + m16) * LSTRIDE + quad * 8];

    f32x4 acc[NT];
#pragma unroll
    for (int nt = 0; nt < NT; nt++) acc[nt] = f32x4{0.f, 0.f, 0.f, 0.f};

#pragma unroll
    for (int ks = 0; ks < KS; ks++) {
        BF8 af;
        af.u = *(const uint4*)(Afrag0 + ks * 32);
#pragma unroll
        for (int nt = 0; nt < NT; nt++) {
            BF8 bf;
            bf.u = *(const uint4*)(Bb0 + (size_t)nt * 16 * K + ks * 32);
            acc[nt] = __builtin_amdgcn_mfma_f32_16x16x32_bf16(af.s, bf.s, acc[nt], 0, 0, 0);
        }
    }

    const int rowOut = rowBase + wave * 16 + quad * 4;
#pragma unroll
    for (int nt = 0; nt < NT; nt++) {
#pragma unroll
        for (int r = 0; r < 4; r++) {
            int row = rowOut + r;
            if (row < M)
                C[(size_t)row * NCOL + nt * 16 + m16] = f32_to_bf16_rne(acc[nt][r]);
        }
    }
}

extern "C" void kernel_launch(void* const* d_in, const int* in_sizes, int n_in,
                              void* d_out, int out_size, void* d_ws, size_t ws_size,
                              hipStream_t stream) {
    const float* x  = (const float*)d_in[0];
    const int*   ei = (const int*)d_in[1];   // [2, E] flat: src row then dst row
    const float* W1 = (const float*)d_in[2];
    const float* b1 = (const float*)d_in[3];
    const float* W2 = (const float*)d_in[4];
    const float* b2 = (const float*)d_in[5];
    float* out = (float*)d_out;

    const int IN_C = 256;
    const int N = in_sizes[0] / IN_C;
    const int E = in_sizes[1] / 2;
    const int* srcA = ei;
    const int* dstA = ei + E;

    char* ws = (char*)d_ws;
    const size_t KB = 1024, MB = 1024 * 1024;
    int*            counts  = (int*)(ws);                    // N ints
    float*          dinv    = (float*)(ws + 256 * KB);       // N floats
    int*            rowptr  = (int*)(ws + 512 * KB);         // N+1 ints
    int*            bcursor = (int*)(ws + 768 * KB);         // <=256 ints
    int*            bsums   = (int*)(ws + 992 * KB);         // ~64 ints
    unsigned short* w1t     = (unsigned short*)(ws + 1 * MB);           // 128x256 bf16
    unsigned short* w2t     = (unsigned short*)(ws + 1 * MB + 64 * KB); // 64x128 bf16
    int2*           sedge   = (int2*)(ws + 2 * MB);          // E int2 (6.4 MB)
    int2*           tmp     = (int2*)(ws + 9 * MB);          // E int2 (6.4 MB)
    unsigned short* h1b     = (unsigned short*)(ws + 16 * MB); // N*128 bf16 (12.8 MB)
    unsigned short* a1b     = (unsigned short*)(ws + 29 * MB); // N*128 bf16 (12.8 MB)
    unsigned short* h2b     = h1b;                           // reuse (N*64 bf16)

    const int nb256 = (N + 255) / 256;
    const int eb256 = (E + 255) / 256;
    const int nbScan = (N + 1 + 1023) / 1024;
    const int NB = (N + 255) / 256;           // coarse buckets (<=256)
    const int gGemm = (N + 63) / 64;

    // ---- CSR build + weight prep ----
    zero_int_kernel<<<nb256, 256, 0, stream>>>(counts, N);
    count_deg_kernel<<<eb256, 256, 0, stream>>>(dstA, counts, E);
    wtrans_kernel<<<(256 * 128 + 128 * 64 + 255) / 256, 256, 0, stream>>>(W1, W2, w1t, w2t);
    scan_partial_kernel<<<nbScan, 256, 0, stream>>>(counts, bsums, dinv, N);
    scan_bsums_kernel<<<1, 64, 0, stream>>>(bsums, nbScan);
    scan_final_kernel<<<nbScan, 256, 0, stream>>>(counts, bsums, rowptr, N);
    init_bcursor_kernel<<<(NB + 255) / 256, 256, 0, stream>>>(rowptr, bcursor, NB);
    bucketA_kernel<<<(E + ACHUNK - 1) / ACHUNK, 256, 0, stream>>>(srcA, dstA, bcursor, tmp, E, NB);
    bucketB_kernel<<<NB, 256, 0, stream>>>(rowptr, tmp, dinv, sedge, N);

    // ---- layer 1: h1 = bf16(x) @ bf16(W1) ; a1 = bf16(relu(agg + b1)) ----
    mfma_gemm_kernel<8, 8, false><<<gGemm, 256, 0, stream>>>(x, w1t, h1b, N);
    agg128_kernel<<<(N + 3) / 4, 256, 0, stream>>>(rowptr, sedge, h1b, dinv, b1, a1b, N);

    // ---- layer 2: h2 = a1 @ bf16(W2) ; out = agg + b2 (f32) ----
    mfma_gemm_kernel<4, 4, true><<<gGemm, 256, 0, stream>>>(a1b, w2t, h2b, N);
    agg64_kernel<<<(N + 3) / 4, 256, 0, stream>>>(rowptr, sedge, h2b, dinv, b2, out, N);
}

// Round 9
// 258.955 us; speedup vs baseline: 4.0657x; 1.0781x over previous
//
#include <hip/hip_runtime.h>
#include <hip/hip_bf16.h>

// ---------------------------------------------------------------------------
// 2-layer GCN forward on MI355X — round 9.
// R8 post-mortem: coalescing A-staging changed nothing -> A wasn't the limit.
// Constant across R6/R7/R8: B-fragment loads touch 16 cache lines each
// (m16-lanes 512B apart) -> TA address-divergence serialization ~20µs/CU.
// Fix: weights repacked in FRAGMENT-LINEAR layout (wf[(nt*KS+ks)*64+lane]
// = the uint4 lane needs) -> every B load is 1KB contiguous, L1-broadcast.
// Also: A staging as explicit load-8/write-8 batches; A-LDS pad K+8 (2-way).
// ---------------------------------------------------------------------------

typedef __attribute__((ext_vector_type(8))) short short8;
typedef __attribute__((ext_vector_type(4))) float f32x4;

union BF8 {
    short8 s;
    uint4 u;
    __hip_bfloat162 h[4];
};

__device__ __forceinline__ unsigned short f32_to_bf16_rne(float f) {
    unsigned u = __float_as_uint(f);
    return (unsigned short)((u + 0x7fffu + ((u >> 16) & 1u)) >> 16);
}
__device__ __forceinline__ float bf_lo(unsigned v) { return __uint_as_float(v << 16); }
__device__ __forceinline__ float bf_hi(unsigned v) { return __uint_as_float(v & 0xffff0000u); }

__global__ void zero_int_kernel(int* __restrict__ p, int n) {
    int i = blockIdx.x * blockDim.x + threadIdx.x;
    if (i < n) p[i] = 0;
}

__global__ void count_deg_kernel(const int* __restrict__ dst, int* __restrict__ counts, int e) {
    int i = blockIdx.x * blockDim.x + threadIdx.x;
    if (i < e) atomicAdd(&counts[dst[i]], 1);
}

// Repack W[K][N] f32 -> fragment-linear bf16: wf[((nt*KS+ks)*64 + lane)*8 + j]
// = bf16(W[ks*32 + (lane>>4)*8 + j][nt*16 + (lane&15)]).
// One launch handles both weights: first 32768 elems -> w1f, next 8192 -> w2f.
__global__ void wfrag_kernel(const float* __restrict__ W1, const float* __restrict__ W2,
                             unsigned short* __restrict__ w1f, unsigned short* __restrict__ w2f) {
    int i = blockIdx.x * blockDim.x + threadIdx.x;
    const float* W;
    unsigned short* WF;
    int KS, NCOL, idx;
    if (i < 32768) {            // W1: KS=8, NT=8, N=128
        W = W1; WF = w1f; KS = 8; NCOL = 128; idx = i;
    } else if (i < 32768 + 8192) {  // W2: KS=4, NT=4, N=64
        W = W2; WF = w2f; KS = 4; NCOL = 64; idx = i - 32768;
    } else return;
    int j = idx & 7;
    int lane = (idx >> 3) & 63;
    int f = idx >> 9;           // nt*KS + ks
    int ks = f % KS, nt = f / KS;
    int m16 = lane & 15, quad = lane >> 4;
    int n = nt * 16 + m16;
    int k = ks * 32 + quad * 8 + j;
    WF[idx] = f32_to_bf16_rne(W[k * NCOL + n]);
}

// ---- Hierarchical exclusive scan over counts[0..n) -> rowptr[0..n] ----
__global__ __launch_bounds__(256) void scan_partial_kernel(const int* __restrict__ counts,
                                                           int* __restrict__ bsums,
                                                           float* __restrict__ dinv, int n) {
    __shared__ int wsum[4];
    const int tid = threadIdx.x;
    const int lane = tid & 63, wv = tid >> 6;
    int base = blockIdx.x * 1024 + tid * 4;
    int s = 0;
#pragma unroll
    for (int j = 0; j < 4; j++) {
        int i = base + j;
        if (i < n) {
            int c = counts[i];
            s += c;
            dinv[i] = rsqrtf((float)c + 1.0f);
        }
    }
#pragma unroll
    for (int off = 1; off < 64; off <<= 1) {
        int y = __shfl_up(s, off, 64);
        if (lane >= off) s += y;
    }
    if (lane == 63) wsum[wv] = s;
    __syncthreads();
    if (tid == 0) bsums[blockIdx.x] = wsum[0] + wsum[1] + wsum[2] + wsum[3];
}

__global__ void scan_bsums_kernel(int* __restrict__ bsums, int nb) {
    int lane = threadIdx.x;
    int carry = 0;
    for (int base = 0; base < nb; base += 64) {
        int i = base + lane;
        int v = (i < nb) ? bsums[i] : 0;
        int x = v;
#pragma unroll
        for (int off = 1; off < 64; off <<= 1) {
            int y = __shfl_up(x, off, 64);
            if (lane >= off) x += y;
        }
        if (i < nb) bsums[i] = carry + x - v;  // exclusive
        carry += __shfl(x, 63, 64);
    }
}

__global__ __launch_bounds__(256) void scan_final_kernel(const int* __restrict__ counts,
                                                         const int* __restrict__ bsums,
                                                         int* __restrict__ rowptr, int n) {
    __shared__ int wsum[4];
    const int tid = threadIdx.x;
    const int lane = tid & 63, wv = tid >> 6;
    int base = blockIdx.x * 1024 + tid * 4;
    int v[4];
#pragma unroll
    for (int j = 0; j < 4; j++) {
        int i = base + j;
        v[j] = (i < n) ? counts[i] : 0;
    }
    int tot = v[0] + v[1] + v[2] + v[3];
    int x = tot;
#pragma unroll
    for (int off = 1; off < 64; off <<= 1) {
        int y = __shfl_up(x, off, 64);
        if (lane >= off) x += y;
    }
    if (lane == 63) wsum[wv] = x;
    __syncthreads();
    int wpre = 0;
    for (int k = 0; k < wv; k++) wpre += wsum[k];
    int pre = bsums[blockIdx.x] + wpre + (x - tot);
#pragma unroll
    for (int j = 0; j < 4; j++) {
        int i = base + j;
        if (i <= n) rowptr[i] = pre;
        pre += v[j];
    }
}

// bcursor[b] = rowptr[b*256]
__global__ void init_bcursor_kernel(const int* __restrict__ rowptr, int* __restrict__ bcursor,
                                    int nb) {
    int b = blockIdx.x * blockDim.x + threadIdx.x;
    if (b < nb) bcursor[b] = rowptr[b * 256];
}

// ---- Phase A: coarse scatter of (src,dst) into tmp, bucketed by dst>>8 ----
#define ACHUNK 2048
__global__ __launch_bounds__(256) void bucketA_kernel(const int* __restrict__ src,
                                                      const int* __restrict__ dst,
                                                      int* __restrict__ bcursor,
                                                      int2* __restrict__ tmp, int e, int nb) {
    __shared__ int sdst[ACHUNK];
    __shared__ int hist[256];   // nb <= 256
    const int tid = threadIdx.x;
    const int start = blockIdx.x * ACHUNK;
    const int cnt = min(ACHUNK, e - start);
    if (tid < nb) hist[tid] = 0;
    __syncthreads();
    for (int i = tid; i < cnt; i += 256) {
        int d = dst[start + i];
        sdst[i] = d;
        atomicAdd(&hist[d >> 8], 1);
    }
    __syncthreads();
    if (tid < nb) {
        int h = hist[tid];
        hist[tid] = (h > 0) ? atomicAdd(&bcursor[tid], h) : 0;
    }
    __syncthreads();
    for (int i = tid; i < cnt; i += 256) {
        int d = sdst[i];
        int slot = atomicAdd(&hist[d >> 8], 1);
        tmp[slot] = make_int2(src[start + i], d);
    }
}

// ---- Phase B: one block per bucket; finalize CSR records (src, weight) ----
__global__ __launch_bounds__(256) void bucketB_kernel(const int* __restrict__ rowptr,
                                                      const int2* __restrict__ tmp,
                                                      const float* __restrict__ dinv,
                                                      int2* __restrict__ sedge, int n) {
    __shared__ int lcur[256];
    __shared__ float ldinv[256];
    const int tid = threadIdx.x;
    const int nodeBase = blockIdx.x * 256;
    const int nNodes = min(256, n - nodeBase);
    if (tid < nNodes) {
        lcur[tid] = rowptr[nodeBase + tid];
        ldinv[tid] = dinv[nodeBase + tid];
    }
    __syncthreads();
    const int beg = rowptr[nodeBase];
    const int end = rowptr[nodeBase + nNodes];
    for (int i = beg + tid; i < end; i += 256) {
        int2 r = tmp[i];
        int j = r.y - nodeBase;
        float w = dinv[r.x] * ldinv[j];
        int pos = atomicAdd(&lcur[j], 1);
        sedge[pos] = make_int2(r.x, __float_as_int(w));
    }
}

// One wave per node, 128 bf16 channels. Writes a1 = bf16(relu(bias + agg)).
__global__ __launch_bounds__(256) void agg128_kernel(
    const int* __restrict__ rowptr, const int2* __restrict__ sedge,
    const unsigned short* __restrict__ hb, const float* __restrict__ dinv,
    const float* __restrict__ bias, unsigned short* __restrict__ outb, int n) {
    int node = blockIdx.x * 4 + (threadIdx.x >> 6);
    if (node >= n) return;
    int lane = threadIdx.x & 63;
    float di = dinv[node];
    unsigned sv = ((const unsigned*)(hb + (size_t)node * 128))[lane];
    float accx = di * di * bf_lo(sv);
    float accy = di * di * bf_hi(sv);
    int beg = rowptr[node], end = rowptr[node + 1];
    int i = beg;
    for (; i + 8 <= end; i += 8) {
        int2 e[8];
        unsigned v[8];
#pragma unroll
        for (int j = 0; j < 8; j++) e[j] = sedge[i + j];
#pragma unroll
        for (int j = 0; j < 8; j++)
            v[j] = ((const unsigned*)(hb + (size_t)e[j].x * 128))[lane];
#pragma unroll
        for (int j = 0; j < 8; j++) {
            float w = __int_as_float(e[j].y);
            accx = fmaf(w, bf_lo(v[j]), accx);
            accy = fmaf(w, bf_hi(v[j]), accy);
        }
    }
    for (; i + 4 <= end; i += 4) {
        int2 e[4];
        unsigned v[4];
#pragma unroll
        for (int j = 0; j < 4; j++) e[j] = sedge[i + j];
#pragma unroll
        for (int j = 0; j < 4; j++)
            v[j] = ((const unsigned*)(hb + (size_t)e[j].x * 128))[lane];
#pragma unroll
        for (int j = 0; j < 4; j++) {
            float w = __int_as_float(e[j].y);
            accx = fmaf(w, bf_lo(v[j]), accx);
            accy = fmaf(w, bf_hi(v[j]), accy);
        }
    }
    for (; i < end; ++i) {
        int2 e = sedge[i];
        float w = __int_as_float(e.y);
        unsigned v = ((const unsigned*)(hb + (size_t)e.x * 128))[lane];
        accx = fmaf(w, bf_lo(v), accx);
        accy = fmaf(w, bf_hi(v), accy);
    }
    float2 bv = *((const float2*)bias + lane);
    float rx = fmaxf(accx + bv.x, 0.0f);
    float ry = fmaxf(accy + bv.y, 0.0f);
    BF8 p;
    p.h[0] = __float22bfloat162_rn(make_float2(rx, ry));
    ((unsigned*)(outb + (size_t)node * 128))[lane] = p.u.x;
}

// One wave per node, 64 bf16 channels. Writes f32 out+bias.
__global__ __launch_bounds__(256) void agg64_kernel(
    const int* __restrict__ rowptr, const int2* __restrict__ sedge,
    const unsigned short* __restrict__ hb, const float* __restrict__ dinv,
    const float* __restrict__ bias, float* __restrict__ out, int n) {
    int node = blockIdx.x * 4 + (threadIdx.x >> 6);
    if (node >= n) return;
    int lane = threadIdx.x & 63;
    float di = dinv[node];
    float acc = di * di * __uint_as_float((unsigned)hb[(size_t)node * 64 + lane] << 16);
    int beg = rowptr[node], end = rowptr[node + 1];
    int i = beg;
    for (; i + 8 <= end; i += 8) {
        int2 e[8];
        float v[8];
#pragma unroll
        for (int j = 0; j < 8; j++) e[j] = sedge[i + j];
#pragma unroll
        for (int j = 0; j < 8; j++)
            v[j] = __uint_as_float((unsigned)hb[(size_t)e[j].x * 64 + lane] << 16);
#pragma unroll
        for (int j = 0; j < 8; j++) acc = fmaf(__int_as_float(e[j].y), v[j], acc);
    }
    for (; i + 4 <= end; i += 4) {
        int2 e[4];
        float v[4];
#pragma unroll
        for (int j = 0; j < 4; j++) e[j] = sedge[i + j];
#pragma unroll
        for (int j = 0; j < 4; j++)
            v[j] = __uint_as_float((unsigned)hb[(size_t)e[j].x * 64 + lane] << 16);
#pragma unroll
        for (int j = 0; j < 4; j++) acc = fmaf(__int_as_float(e[j].y), v[j], acc);
    }
    for (; i < end; ++i) {
        int2 e = sedge[i];
        float v = __uint_as_float((unsigned)hb[(size_t)e.x * 64 + lane] << 16);
        acc = fmaf(__int_as_float(e.y), v, acc);
    }
    out[(size_t)node * 64 + lane] = acc + bias[lane];
}

// ---------------------------------------------------------------------------
// MFMA bf16 GEMM. A staged via coalesced loads -> LDS [64][K+8] bf16 (2-way
// bank alias max). B read from FRAGMENT-LINEAR global layout: frag (nt,ks)
// = 64 consecutive uint4 (lane-ordered) -> fully coalesced, L1-broadcast.
// 4 waves; wave w owns rows [w*16, w*16+16) x all NT*16 cols.
// BFA=false: A f32 (cvt during staging); BFA=true: A bf16.
// ---------------------------------------------------------------------------
template <int NT, int KS, bool BFA>
__global__ __launch_bounds__(256) void mfma_gemm_kernel(
    const void* __restrict__ Av, const unsigned short* __restrict__ BFRAG,
    unsigned short* __restrict__ C, int M) {
    constexpr int NCOL = NT * 16;
    constexpr int K = KS * 32;
    constexpr int LSTRIDE = K + 8;             // byte stride mult of 16; words ≡4 mod 32
    __shared__ unsigned short Alds[64 * LSTRIDE];

    const int tid = threadIdx.x;
    const int wave = tid >> 6, lane = tid & 63;
    const int quad = lane >> 4, m16 = lane & 15;
    const int rowBase = blockIdx.x * 64;

    // ---- stage A: explicit load-batch then write-batch (loads stay in flight)
    if constexpr (BFA) {
        const unsigned short* Ab = (const unsigned short*)Av;
        constexpr int ITERS = K / 32;          // 64*K/(256*8)
        uint4 v[ITERS];
#pragma unroll
        for (int it = 0; it < ITERS; it++) {
            int p = it * 2048 + tid * 8;
            int rg = rowBase + p / K;
            if (rg >= M) rg = M - 1;
            v[it] = *(const uint4*)(Ab + (size_t)rg * K + (p % K));
        }
#pragma unroll
        for (int it = 0; it < ITERS; it++) {
            int p = it * 2048 + tid * 8;
            *(uint4*)&Alds[(p / K) * LSTRIDE + (p % K)] = v[it];
        }
    } else {
        const float* Af = (const float*)Av;
        constexpr int HALVES = K / 128;        // total iters = K/16, batch 8
#pragma unroll
        for (int h = 0; h < HALVES; h++) {
            f32x4 v[8];
#pragma unroll
            for (int it = 0; it < 8; it++) {
                int p = (h * 8 + it) * 1024 + tid * 4;
                int rg = rowBase + p / K;
                if (rg >= M) rg = M - 1;
                v[it] = *(const f32x4*)(Af + (size_t)rg * K + (p % K));
            }
#pragma unroll
            for (int it = 0; it < 8; it++) {
                int p = (h * 8 + it) * 1024 + tid * 4;
                BF8 cv;
                cv.h[0] = __float22bfloat162_rn(make_float2(v[it].x, v[it].y));
                cv.h[1] = __float22bfloat162_rn(make_float2(v[it].z, v[it].w));
                *(uint2*)&Alds[(p / K) * LSTRIDE + (p % K)] = make_uint2(cv.u.x, cv.u.y);
            }
        }
    }
    __syncthreads();

    const unsigned short* Afrag0 = &Alds[(wave * 16 + m16) * LSTRIDE + quad * 8];
    const uint4* Bfrag = (const uint4*)BFRAG + lane;   // + (nt*KS+ks)*64

    f32x4 acc[NT];
#pragma unroll
    for (int nt = 0; nt < NT; nt++) acc[nt] = f32x4{0.f, 0.f, 0.f, 0.f};

#pragma unroll
    for (int ks = 0; ks < KS; ks++) {
        BF8 af;
        af.u = *(const uint4*)(Afrag0 + ks * 32);
#pragma unroll
        for (int nt = 0; nt < NT; nt++) {
            BF8 bf;
            bf.u = Bfrag[(nt * KS + ks) * 64];
            acc[nt] = __builtin_amdgcn_mfma_f32_16x16x32_bf16(af.s, bf.s, acc[nt], 0, 0, 0);
        }
    }

    const int rowOut = rowBase + wave * 16 + quad * 4;
#pragma unroll
    for (int nt = 0; nt < NT; nt++) {
#pragma unroll
        for (int r = 0; r < 4; r++) {
            int row = rowOut + r;
            if (row < M)
                C[(size_t)row * NCOL + nt * 16 + m16] = f32_to_bf16_rne(acc[nt][r]);
        }
    }
}

extern "C" void kernel_launch(void* const* d_in, const int* in_sizes, int n_in,
                              void* d_out, int out_size, void* d_ws, size_t ws_size,
                              hipStream_t stream) {
    const float* x  = (const float*)d_in[0];
    const int*   ei = (const int*)d_in[1];   // [2, E] flat: src row then dst row
    const float* W1 = (const float*)d_in[2];
    const float* b1 = (const float*)d_in[3];
    const float* W2 = (const float*)d_in[4];
    const float* b2 = (const float*)d_in[5];
    float* out = (float*)d_out;

    const int IN_C = 256;
    const int N = in_sizes[0] / IN_C;
    const int E = in_sizes[1] / 2;
    const int* srcA = ei;
    const int* dstA = ei + E;

    char* ws = (char*)d_ws;
    const size_t KB = 1024, MB = 1024 * 1024;
    int*            counts  = (int*)(ws);                    // N ints
    float*          dinv    = (float*)(ws + 256 * KB);       // N floats
    int*            rowptr  = (int*)(ws + 512 * KB);         // N+1 ints
    int*            bcursor = (int*)(ws + 768 * KB);         // <=256 ints
    int*            bsums   = (int*)(ws + 992 * KB);         // ~64 ints
    unsigned short* w1f     = (unsigned short*)(ws + 1 * MB);           // 32768 bf16 (64 KB)
    unsigned short* w2f     = (unsigned short*)(ws + 1 * MB + 64 * KB); // 8192 bf16 (16 KB)
    int2*           sedge   = (int2*)(ws + 2 * MB);          // E int2 (6.4 MB)
    int2*           tmp     = (int2*)(ws + 9 * MB);          // E int2 (6.4 MB)
    unsigned short* h1b     = (unsigned short*)(ws + 16 * MB); // N*128 bf16 (12.8 MB)
    unsigned short* a1b     = (unsigned short*)(ws + 29 * MB); // N*128 bf16 (12.8 MB)
    unsigned short* h2b     = h1b;                           // reuse (N*64 bf16)

    const int nb256 = (N + 255) / 256;
    const int eb256 = (E + 255) / 256;
    const int nbScan = (N + 1 + 1023) / 1024;
    const int NB = (N + 255) / 256;           // coarse buckets (<=256)
    const int gGemm = (N + 63) / 64;

    // ---- CSR build + weight prep ----
    zero_int_kernel<<<nb256, 256, 0, stream>>>(counts, N);
    count_deg_kernel<<<eb256, 256, 0, stream>>>(dstA, counts, E);
    wfrag_kernel<<<(32768 + 8192 + 255) / 256, 256, 0, stream>>>(W1, W2, w1f, w2f);
    scan_partial_kernel<<<nbScan, 256, 0, stream>>>(counts, bsums, dinv, N);
    scan_bsums_kernel<<<1, 64, 0, stream>>>(bsums, nbScan);
    scan_final_kernel<<<nbScan, 256, 0, stream>>>(counts, bsums, rowptr, N);
    init_bcursor_kernel<<<(NB + 255) / 256, 256, 0, stream>>>(rowptr, bcursor, NB);
    bucketA_kernel<<<(E + ACHUNK - 1) / ACHUNK, 256, 0, stream>>>(srcA, dstA, bcursor, tmp, E, NB);
    bucketB_kernel<<<NB, 256, 0, stream>>>(rowptr, tmp, dinv, sedge, N);

    // ---- layer 1: h1 = bf16(x) @ bf16(W1) ; a1 = bf16(relu(agg + b1)) ----
    mfma_gemm_kernel<8, 8, false><<<gGemm, 256, 0, stream>>>(x, w1f, h1b, N);
    agg128_kernel<<<(N + 3) / 4, 256, 0, stream>>>(rowptr, sedge, h1b, dinv, b1, a1b, N);

    // ---- layer 2: h2 = a1 @ bf16(W2) ; out = agg + b2 (f32) ----
    mfma_gemm_kernel<4, 4, true><<<gGemm, 256, 0, stream>>>(a1b, w2f, h2b, N);
    agg64_kernel<<<(N + 3) / 4, 256, 0, stream>>>(rowptr, sedge, h2b, dinv, b2, out, N);
}

// Round 10
// 243.236 us; speedup vs baseline: 4.3284x; 1.0646x over previous
//
#include <hip/hip_runtime.h>
#include <hip/hip_bf16.h>

// ---------------------------------------------------------------------------
// 2-layer GCN forward on MI355X — round 10.
// R9 post-mortem: B fragment-linear repack worked (gemm1 out of top-5).
// Remaining: agg kernels' per-node dependent gather chain (mean deg 16).
// Changes:
//  (1) agg128/agg64: TWO nodes per wave (half-wave each) -> wave retires 2
//      nodes in max(dA,dB) iterations instead of dA+dB (exec-masked loop).
//  (2) zero_int folded into wfrag; scan_bsums + init_bcursor folded into
//      scan_final (49 block-sums scanned by wave 0 in-kernel). 13->10 kernels.
// ---------------------------------------------------------------------------

typedef __attribute__((ext_vector_type(8))) short short8;
typedef __attribute__((ext_vector_type(4))) float f32x4;

union BF8 {
    short8 s;
    uint4 u;
    __hip_bfloat162 h[4];
};

__device__ __forceinline__ unsigned short f32_to_bf16_rne(float f) {
    unsigned u = __float_as_uint(f);
    return (unsigned short)((u + 0x7fffu + ((u >> 16) & 1u)) >> 16);
}
__device__ __forceinline__ float bf_lo(unsigned v) { return __uint_as_float(v << 16); }
__device__ __forceinline__ float bf_hi(unsigned v) { return __uint_as_float(v & 0xffff0000u); }

__global__ void count_deg_kernel(const int* __restrict__ dst, int* __restrict__ counts, int e) {
    int i = blockIdx.x * blockDim.x + threadIdx.x;
    if (i < e) atomicAdd(&counts[dst[i]], 1);
}

// Repack W[K][N] f32 -> fragment-linear bf16 AND zero counts[0..n).
// wf[((nt*KS+ks)*64 + lane)*8 + j] = bf16(W[ks*32+(lane>>4)*8+j][nt*16+(lane&15)]).
__global__ void wfrag_zero_kernel(const float* __restrict__ W1, const float* __restrict__ W2,
                                  unsigned short* __restrict__ w1f,
                                  unsigned short* __restrict__ w2f,
                                  int* __restrict__ counts, int n) {
    int i = blockIdx.x * blockDim.x + threadIdx.x;
    if (i < n) counts[i] = 0;
    const float* W;
    unsigned short* WF;
    int KS, NCOL, idx;
    if (i < 32768) {            // W1: KS=8, NT=8, N=128
        W = W1; WF = w1f; KS = 8; NCOL = 128; idx = i;
    } else if (i < 32768 + 8192) {  // W2: KS=4, NT=4, N=64
        W = W2; WF = w2f; KS = 4; NCOL = 64; idx = i - 32768;
    } else return;
    int j = idx & 7;
    int lane = (idx >> 3) & 63;
    int f = idx >> 9;           // nt*KS + ks
    int ks = f % KS, nt = f / KS;
    int m16 = lane & 15, quad = lane >> 4;
    int ncol = nt * 16 + m16;
    int k = ks * 32 + quad * 8 + j;
    WF[idx] = f32_to_bf16_rne(W[k * NCOL + ncol]);
}

// ---- Hierarchical exclusive scan over counts[0..n) -> rowptr[0..n] ----
// Phase A: per-1024-chunk sums; also emits dinv.
__global__ __launch_bounds__(256) void scan_partial_kernel(const int* __restrict__ counts,
                                                           int* __restrict__ bsums,
                                                           float* __restrict__ dinv, int n) {
    __shared__ int wsum[4];
    const int tid = threadIdx.x;
    const int lane = tid & 63, wv = tid >> 6;
    int base = blockIdx.x * 1024 + tid * 4;
    int s = 0;
#pragma unroll
    for (int j = 0; j < 4; j++) {
        int i = base + j;
        if (i < n) {
            int c = counts[i];
            s += c;
            dinv[i] = rsqrtf((float)c + 1.0f);
        }
    }
#pragma unroll
    for (int off = 1; off < 64; off <<= 1) {
        int y = __shfl_up(s, off, 64);
        if (lane >= off) s += y;
    }
    if (lane == 63) wsum[wv] = s;
    __syncthreads();
    if (tid == 0) bsums[blockIdx.x] = wsum[0] + wsum[1] + wsum[2] + wsum[3];
}

// Phase B (fused): wave 0 scans the <=64 block sums in-register; then the
// block re-scans its chunk, writes rowptr[0..n] and bcursor (bucket starts).
__global__ __launch_bounds__(256) void scan_final_kernel(const int* __restrict__ counts,
                                                         const int* __restrict__ bsums,
                                                         int* __restrict__ rowptr,
                                                         int* __restrict__ bcursor,
                                                         int n, int nb) {
    __shared__ int wsum[4];
    __shared__ int blockOff;
    const int tid = threadIdx.x;
    const int lane = tid & 63, wv = tid >> 6;
    if (tid < 64) {   // nb <= 64 (supports N up to 65536)
        int v = (tid < nb) ? bsums[tid] : 0;
        int x = v;
#pragma unroll
        for (int off = 1; off < 64; off <<= 1) {
            int y = __shfl_up(x, off, 64);
            if (lane >= off) x += y;
        }
        int pref = (blockIdx.x == 0) ? 0 : __shfl(x, blockIdx.x - 1, 64);
        if (tid == 0) blockOff = pref;
    }
    int base = blockIdx.x * 1024 + tid * 4;
    int v[4];
#pragma unroll
    for (int j = 0; j < 4; j++) {
        int i = base + j;
        v[j] = (i < n) ? counts[i] : 0;
    }
    int tot = v[0] + v[1] + v[2] + v[3];
    int x = tot;
#pragma unroll
    for (int off = 1; off < 64; off <<= 1) {
        int y = __shfl_up(x, off, 64);
        if (lane >= off) x += y;
    }
    if (lane == 63) wsum[wv] = x;
    __syncthreads();
    int wpre = 0;
    for (int k = 0; k < wv; k++) wpre += wsum[k];
    int pre = blockOff + wpre + (x - tot);
#pragma unroll
    for (int j = 0; j < 4; j++) {
        int i = base + j;
        if (i <= n) rowptr[i] = pre;
        if (i < n && (i & 255) == 0) bcursor[i >> 8] = pre;
        pre += v[j];
    }
}

// ---- Phase A: coarse scatter of (src,dst) into tmp, bucketed by dst>>8 ----
#define ACHUNK 2048
__global__ __launch_bounds__(256) void bucketA_kernel(const int* __restrict__ src,
                                                      const int* __restrict__ dst,
                                                      int* __restrict__ bcursor,
                                                      int2* __restrict__ tmp, int e, int nb) {
    __shared__ int sdst[ACHUNK];
    __shared__ int hist[256];   // nb <= 256
    const int tid = threadIdx.x;
    const int start = blockIdx.x * ACHUNK;
    const int cnt = min(ACHUNK, e - start);
    if (tid < nb) hist[tid] = 0;
    __syncthreads();
    for (int i = tid; i < cnt; i += 256) {
        int d = dst[start + i];
        sdst[i] = d;
        atomicAdd(&hist[d >> 8], 1);
    }
    __syncthreads();
    if (tid < nb) {
        int h = hist[tid];
        hist[tid] = (h > 0) ? atomicAdd(&bcursor[tid], h) : 0;
    }
    __syncthreads();
    for (int i = tid; i < cnt; i += 256) {
        int d = sdst[i];
        int slot = atomicAdd(&hist[d >> 8], 1);
        tmp[slot] = make_int2(src[start + i], d);
    }
}

// ---- Phase B: one block per bucket; finalize CSR records (src, weight) ----
__global__ __launch_bounds__(256) void bucketB_kernel(const int* __restrict__ rowptr,
                                                      const int2* __restrict__ tmp,
                                                      const float* __restrict__ dinv,
                                                      int2* __restrict__ sedge, int n) {
    __shared__ int lcur[256];
    __shared__ float ldinv[256];
    const int tid = threadIdx.x;
    const int nodeBase = blockIdx.x * 256;
    const int nNodes = min(256, n - nodeBase);
    if (tid < nNodes) {
        lcur[tid] = rowptr[nodeBase + tid];
        ldinv[tid] = dinv[nodeBase + tid];
    }
    __syncthreads();
    const int beg = rowptr[nodeBase];
    const int end = rowptr[nodeBase + nNodes];
    for (int i = beg + tid; i < end; i += 256) {
        int2 r = tmp[i];
        int j = r.y - nodeBase;
        float w = dinv[r.x] * ldinv[j];
        int pos = atomicAdd(&lcur[j], 1);
        sedge[pos] = make_int2(r.x, __float_as_int(w));
    }
}

// TWO nodes per wave (half-wave each), 128 bf16 channels -> 4 ch/lane (uint2).
// Writes a1 = bf16(relu(bias + dinv^2*h_self + sum w*h_src)).
__global__ __launch_bounds__(256) void agg128_kernel(
    const int* __restrict__ rowptr, const int2* __restrict__ sedge,
    const unsigned short* __restrict__ hb, const float* __restrict__ dinv,
    const float* __restrict__ bias, unsigned short* __restrict__ outb, int n) {
    int node = blockIdx.x * 8 + (threadIdx.x >> 5);
    if (node >= n) return;
    int sub = threadIdx.x & 31;
    float di = dinv[node];
    float d2 = di * di;
    uint2 sv = ((const uint2*)(hb + (size_t)node * 128))[sub];
    float a0 = d2 * bf_lo(sv.x), a1 = d2 * bf_hi(sv.x);
    float a2 = d2 * bf_lo(sv.y), a3 = d2 * bf_hi(sv.y);
    int beg = rowptr[node], end = rowptr[node + 1];
    int i = beg;
    for (; i + 8 <= end; i += 8) {
        int2 e[8];
        uint2 v[8];
#pragma unroll
        for (int j = 0; j < 8; j++) e[j] = sedge[i + j];
#pragma unroll
        for (int j = 0; j < 8; j++)
            v[j] = ((const uint2*)(hb + (size_t)e[j].x * 128))[sub];
#pragma unroll
        for (int j = 0; j < 8; j++) {
            float w = __int_as_float(e[j].y);
            a0 = fmaf(w, bf_lo(v[j].x), a0);
            a1 = fmaf(w, bf_hi(v[j].x), a1);
            a2 = fmaf(w, bf_lo(v[j].y), a2);
            a3 = fmaf(w, bf_hi(v[j].y), a3);
        }
    }
    for (; i + 4 <= end; i += 4) {
        int2 e[4];
        uint2 v[4];
#pragma unroll
        for (int j = 0; j < 4; j++) e[j] = sedge[i + j];
#pragma unroll
        for (int j = 0; j < 4; j++)
            v[j] = ((const uint2*)(hb + (size_t)e[j].x * 128))[sub];
#pragma unroll
        for (int j = 0; j < 4; j++) {
            float w = __int_as_float(e[j].y);
            a0 = fmaf(w, bf_lo(v[j].x), a0);
            a1 = fmaf(w, bf_hi(v[j].x), a1);
            a2 = fmaf(w, bf_lo(v[j].y), a2);
            a3 = fmaf(w, bf_hi(v[j].y), a3);
        }
    }
    for (; i < end; ++i) {
        int2 e = sedge[i];
        float w = __int_as_float(e.y);
        uint2 v = ((const uint2*)(hb + (size_t)e.x * 128))[sub];
        a0 = fmaf(w, bf_lo(v.x), a0);
        a1 = fmaf(w, bf_hi(v.x), a1);
        a2 = fmaf(w, bf_lo(v.y), a2);
        a3 = fmaf(w, bf_hi(v.y), a3);
    }
    float4 bv = ((const float4*)bias)[sub];
    float r0 = fmaxf(a0 + bv.x, 0.0f);
    float r1 = fmaxf(a1 + bv.y, 0.0f);
    float r2 = fmaxf(a2 + bv.z, 0.0f);
    float r3 = fmaxf(a3 + bv.w, 0.0f);
    BF8 p;
    p.h[0] = __float22bfloat162_rn(make_float2(r0, r1));
    p.h[1] = __float22bfloat162_rn(make_float2(r2, r3));
    ((uint2*)(outb + (size_t)node * 128))[sub] = make_uint2(p.u.x, p.u.y);
}

// TWO nodes per wave, 64 bf16 channels -> 2 ch/lane (uint). Writes f32 out.
__global__ __launch_bounds__(256) void agg64_kernel(
    const int* __restrict__ rowptr, const int2* __restrict__ sedge,
    const unsigned short* __restrict__ hb, const float* __restrict__ dinv,
    const float* __restrict__ bias, float* __restrict__ out, int n) {
    int node = blockIdx.x * 8 + (threadIdx.x >> 5);
    if (node >= n) return;
    int sub = threadIdx.x & 31;
    float di = dinv[node];
    float d2 = di * di;
    unsigned sv = ((const unsigned*)(hb + (size_t)node * 64))[sub];
    float ax = d2 * bf_lo(sv), ay = d2 * bf_hi(sv);
    int beg = rowptr[node], end = rowptr[node + 1];
    int i = beg;
    for (; i + 8 <= end; i += 8) {
        int2 e[8];
        unsigned v[8];
#pragma unroll
        for (int j = 0; j < 8; j++) e[j] = sedge[i + j];
#pragma unroll
        for (int j = 0; j < 8; j++)
            v[j] = ((const unsigned*)(hb + (size_t)e[j].x * 64))[sub];
#pragma unroll
        for (int j = 0; j < 8; j++) {
            float w = __int_as_float(e[j].y);
            ax = fmaf(w, bf_lo(v[j]), ax);
            ay = fmaf(w, bf_hi(v[j]), ay);
        }
    }
    for (; i + 4 <= end; i += 4) {
        int2 e[4];
        unsigned v[4];
#pragma unroll
        for (int j = 0; j < 4; j++) e[j] = sedge[i + j];
#pragma unroll
        for (int j = 0; j < 4; j++)
            v[j] = ((const unsigned*)(hb + (size_t)e[j].x * 64))[sub];
#pragma unroll
        for (int j = 0; j < 4; j++) {
            float w = __int_as_float(e[j].y);
            ax = fmaf(w, bf_lo(v[j]), ax);
            ay = fmaf(w, bf_hi(v[j]), ay);
        }
    }
    for (; i < end; ++i) {
        int2 e = sedge[i];
        float w = __int_as_float(e.y);
        unsigned v = ((const unsigned*)(hb + (size_t)e.x * 64))[sub];
        ax = fmaf(w, bf_lo(v), ax);
        ay = fmaf(w, bf_hi(v), ay);
    }
    float2 bv = ((const float2*)bias)[sub];
    ((float2*)(out + (size_t)node * 64))[sub] = make_float2(ax + bv.x, ay + bv.y);
}

// ---------------------------------------------------------------------------
// MFMA bf16 GEMM. A staged via coalesced loads -> LDS [64][K+8] bf16.
// B from fragment-linear global layout (uint4 per lane, contiguous).
// BFA=false: A f32 (cvt during staging); BFA=true: A bf16.
// ---------------------------------------------------------------------------
template <int NT, int KS, bool BFA>
__global__ __launch_bounds__(256) void mfma_gemm_kernel(
    const void* __restrict__ Av, const unsigned short* __restrict__ BFRAG,
    unsigned short* __restrict__ C, int M) {
    constexpr int NCOL = NT * 16;
    constexpr int K = KS * 32;
    constexpr int LSTRIDE = K + 8;
    __shared__ unsigned short Alds[64 * LSTRIDE];

    const int tid = threadIdx.x;
    const int wave = tid >> 6, lane = tid & 63;
    const int quad = lane >> 4, m16 = lane & 15;
    const int rowBase = blockIdx.x * 64;

    if constexpr (BFA) {
        const unsigned short* Ab = (const unsigned short*)Av;
        constexpr int ITERS = K / 32;
        uint4 v[ITERS];
#pragma unroll
        for (int it = 0; it < ITERS; it++) {
            int p = it * 2048 + tid * 8;
            int rg = rowBase + p / K;
            if (rg >= M) rg = M - 1;
            v[it] = *(const uint4*)(Ab + (size_t)rg * K + (p % K));
        }
#pragma unroll
        for (int it = 0; it < ITERS; it++) {
            int p = it * 2048 + tid * 8;
            *(uint4*)&Alds[(p / K) * LSTRIDE + (p % K)] = v[it];
        }
    } else {
        const float* Af = (const float*)Av;
        constexpr int HALVES = K / 128;
#pragma unroll
        for (int h = 0; h < HALVES; h++) {
            f32x4 v[8];
#pragma unroll
            for (int it = 0; it < 8; it++) {
                int p = (h * 8 + it) * 1024 + tid * 4;
                int rg = rowBase + p / K;
                if (rg >= M) rg = M - 1;
                v[it] = *(const f32x4*)(Af + (size_t)rg * K + (p % K));
            }
#pragma unroll
            for (int it = 0; it < 8; it++) {
                int p = (h * 8 + it) * 1024 + tid * 4;
                BF8 cv;
                cv.h[0] = __float22bfloat162_rn(make_float2(v[it].x, v[it].y));
                cv.h[1] = __float22bfloat162_rn(make_float2(v[it].z, v[it].w));
                *(uint2*)&Alds[(p / K) * LSTRIDE + (p % K)] = make_uint2(cv.u.x, cv.u.y);
            }
        }
    }
    __syncthreads();

    const unsigned short* Afrag0 = &Alds[(wave * 16 + m16) * LSTRIDE + quad * 8];
    const uint4* Bfrag = (const uint4*)BFRAG + lane;

    f32x4 acc[NT];
#pragma unroll
    for (int nt = 0; nt < NT; nt++) acc[nt] = f32x4{0.f, 0.f, 0.f, 0.f};

#pragma unroll
    for (int ks = 0; ks < KS; ks++) {
        BF8 af;
        af.u = *(const uint4*)(Afrag0 + ks * 32);
#pragma unroll
        for (int nt = 0; nt < NT; nt++) {
            BF8 bf;
            bf.u = Bfrag[(nt * KS + ks) * 64];
            acc[nt] = __builtin_amdgcn_mfma_f32_16x16x32_bf16(af.s, bf.s, acc[nt], 0, 0, 0);
        }
    }

    const int rowOut = rowBase + wave * 16 + quad * 4;
#pragma unroll
    for (int nt = 0; nt < NT; nt++) {
#pragma unroll
        for (int r = 0; r < 4; r++) {
            int row = rowOut + r;
            if (row < M)
                C[(size_t)row * NCOL + nt * 16 + m16] = f32_to_bf16_rne(acc[nt][r]);
        }
    }
}

extern "C" void kernel_launch(void* const* d_in, const int* in_sizes, int n_in,
                              void* d_out, int out_size, void* d_ws, size_t ws_size,
                              hipStream_t stream) {
    const float* x  = (const float*)d_in[0];
    const int*   ei = (const int*)d_in[1];   // [2, E] flat: src row then dst row
    const float* W1 = (const float*)d_in[2];
    const float* b1 = (const float*)d_in[3];
    const float* W2 = (const float*)d_in[4];
    const float* b2 = (const float*)d_in[5];
    float* out = (float*)d_out;

    const int IN_C = 256;
    const int N = in_sizes[0] / IN_C;
    const int E = in_sizes[1] / 2;
    const int* srcA = ei;
    const int* dstA = ei + E;

    char* ws = (char*)d_ws;
    const size_t KB = 1024, MB = 1024 * 1024;
    int*            counts  = (int*)(ws);                    // N ints
    float*          dinv    = (float*)(ws + 256 * KB);       // N floats
    int*            rowptr  = (int*)(ws + 512 * KB);         // N+1 ints
    int*            bcursor = (int*)(ws + 768 * KB);         // <=256 ints
    int*            bsums   = (int*)(ws + 992 * KB);         // ~64 ints
    unsigned short* w1f     = (unsigned short*)(ws + 1 * MB);           // 32768 bf16
    unsigned short* w2f     = (unsigned short*)(ws + 1 * MB + 64 * KB); // 8192 bf16
    int2*           sedge   = (int2*)(ws + 2 * MB);          // E int2 (6.4 MB)
    int2*           tmp     = (int2*)(ws + 9 * MB);          // E int2 (6.4 MB)
    unsigned short* h1b     = (unsigned short*)(ws + 16 * MB); // N*128 bf16
    unsigned short* a1b     = (unsigned short*)(ws + 29 * MB); // N*128 bf16
    unsigned short* h2b     = h1b;                           // reuse (N*64 bf16)

    const int eb256 = (E + 255) / 256;
    const int nbScan = (N + 1 + 1023) / 1024;  // <=64 (N<=65536)
    const int NB = (N + 255) / 256;            // coarse buckets (<=256)
    const int gGemm = (N + 63) / 64;
    const int gWfrag = (max(N, 32768 + 8192) + 255) / 256;

    // ---- CSR build + weight prep ----
    wfrag_zero_kernel<<<gWfrag, 256, 0, stream>>>(W1, W2, w1f, w2f, counts, N);
    count_deg_kernel<<<eb256, 256, 0, stream>>>(dstA, counts, E);
    scan_partial_kernel<<<nbScan, 256, 0, stream>>>(counts, bsums, dinv, N);
    scan_final_kernel<<<nbScan, 256, 0, stream>>>(counts, bsums, rowptr, bcursor, N, nbScan);
    bucketA_kernel<<<(E + ACHUNK - 1) / ACHUNK, 256, 0, stream>>>(srcA, dstA, bcursor, tmp, E, NB);
    bucketB_kernel<<<NB, 256, 0, stream>>>(rowptr, tmp, dinv, sedge, N);

    // ---- layer 1: h1 = bf16(x) @ bf16(W1) ; a1 = bf16(relu(agg + b1)) ----
    mfma_gemm_kernel<8, 8, false><<<gGemm, 256, 0, stream>>>(x, w1f, h1b, N);
    agg128_kernel<<<(N + 7) / 8, 256, 0, stream>>>(rowptr, sedge, h1b, dinv, b1, a1b, N);

    // ---- layer 2: h2 = a1 @ bf16(W2) ; out = agg + b2 (f32) ----
    mfma_gemm_kernel<4, 4, true><<<gGemm, 256, 0, stream>>>(a1b, w2f, h2b, N);
    agg64_kernel<<<(N + 7) / 8, 256, 0, stream>>>(rowptr, sedge, h2b, dinv, b2, out, N);
}

// Round 11
// 227.850 us; speedup vs baseline: 4.6207x; 1.0675x over previous
//
#include <hip/hip_runtime.h>
#include <hip/hip_bf16.h>

// ---------------------------------------------------------------------------
// 2-layer GCN forward on MI355X — round 11.
// R10 post-mortem: top-5 all harness poison fills; our kernels <41 µs each.
// Budget: ~45 µs launch gaps + aggs. Changes:
//  (1) aggs: FOUR nodes per wave (16 lanes/node) -> 1 gather instr = 4 edges.
//  (2) scan collapsed to one decoupled-lookback kernel (49 co-resident blocks).
//  (3) bucketA fused into gemm1 dispatch (grid split, smem union).
//  10 -> 7 kernels.
// ---------------------------------------------------------------------------

typedef __attribute__((ext_vector_type(8))) short short8;
typedef __attribute__((ext_vector_type(4))) float f32x4;

union BF8 {
    short8 s;
    uint4 u;
    __hip_bfloat162 h[4];
};

__device__ __forceinline__ unsigned short f32_to_bf16_rne(float f) {
    unsigned u = __float_as_uint(f);
    return (unsigned short)((u + 0x7fffu + ((u >> 16) & 1u)) >> 16);
}
__device__ __forceinline__ float bf_lo(unsigned v) { return __uint_as_float(v << 16); }
__device__ __forceinline__ float bf_hi(unsigned v) { return __uint_as_float(v & 0xffff0000u); }

__global__ void count_deg_kernel(const int* __restrict__ dst, int* __restrict__ counts, int e) {
    int i = blockIdx.x * blockDim.x + threadIdx.x;
    if (i < e) atomicAdd(&counts[dst[i]], 1);
}

// Repack weights fragment-linear bf16 AND zero counts[0..n) AND zero bflag.
__global__ void wfrag_zero_kernel(const float* __restrict__ W1, const float* __restrict__ W2,
                                  unsigned short* __restrict__ w1f,
                                  unsigned short* __restrict__ w2f,
                                  int* __restrict__ counts, int* __restrict__ bflag, int n) {
    int i = blockIdx.x * blockDim.x + threadIdx.x;
    if (i < n) counts[i] = 0;
    if (i < 64) bflag[i] = 0;
    const float* W;
    unsigned short* WF;
    int KS, NCOL, idx;
    if (i < 32768) {            // W1: KS=8, NT=8, N=128
        W = W1; WF = w1f; KS = 8; NCOL = 128; idx = i;
    } else if (i < 32768 + 8192) {  // W2: KS=4, NT=4, N=64
        W = W2; WF = w2f; KS = 4; NCOL = 64; idx = i - 32768;
    } else return;
    int j = idx & 7;
    int lane = (idx >> 3) & 63;
    int f = idx >> 9;           // nt*KS + ks
    int ks = f % KS, nt = f / KS;
    int m16 = lane & 15, quad = lane >> 4;
    int ncol = nt * 16 + m16;
    int k = ks * 32 + quad * 8 + j;
    WF[idx] = f32_to_bf16_rne(W[k * NCOL + ncol]);
}

// ---- Single-kernel exclusive scan with decoupled lookback ----
// <=64 blocks (N<=65536), all co-resident. Emits rowptr[0..n], bcursor, dinv.
__global__ __launch_bounds__(256) void scan_fused_kernel(const int* __restrict__ counts,
                                                         float* __restrict__ dinv,
                                                         int* __restrict__ rowptr,
                                                         int* __restrict__ bcursor,
                                                         int* __restrict__ bsum,
                                                         int* __restrict__ bflag, int n) {
    __shared__ int wsum[4];
    __shared__ int blockOff;
    const int tid = threadIdx.x;
    const int lane = tid & 63, wv = tid >> 6;
    const int bid = blockIdx.x;
    int base = bid * 1024 + tid * 4;
    int v[4];
#pragma unroll
    for (int j = 0; j < 4; j++) {
        int i = base + j;
        if (i < n) {
            int c = counts[i];
            v[j] = c;
            dinv[i] = rsqrtf((float)c + 1.0f);
        } else v[j] = 0;
    }
    int tot = v[0] + v[1] + v[2] + v[3];
    int x = tot;
#pragma unroll
    for (int off = 1; off < 64; off <<= 1) {
        int y = __shfl_up(x, off, 64);
        if (lane >= off) x += y;
    }
    if (lane == 63) wsum[wv] = x;
    __syncthreads();
    int wpre = 0;
    for (int k = 0; k < wv; k++) wpre += wsum[k];
    // publish block total
    if (tid == 0) {
        bsum[bid] = wsum[0] + wsum[1] + wsum[2] + wsum[3];
        __threadfence();
        atomicExch(&bflag[bid], 1);
    }
    // lookback: wave 0 gathers predecessor sums
    if (wv == 0) {
        int p = 0;
        if (lane < bid) {
            while (atomicAdd(&bflag[lane], 0) == 0) {}
            __threadfence();
            p = atomicAdd(&bsum[lane], 0);
        }
#pragma unroll
        for (int off = 1; off < 64; off <<= 1) p += __shfl_xor(p, off, 64);
        if (lane == 0) blockOff = p;
    }
    __syncthreads();
    int pre = blockOff + wpre + (x - tot);
#pragma unroll
    for (int j = 0; j < 4; j++) {
        int i = base + j;
        if (i <= n) rowptr[i] = pre;
        if (i < n && (i & 255) == 0) bcursor[i >> 8] = pre;
        pre += v[j];
    }
}

// ---------------------------------------------------------------------------
// FUSED: gemm1 (MFMA bf16, f32 A, NT=8 KS=8) + bucketA (coarse edge scatter).
// Blocks [0, gGemm) do GEMM tiles; blocks [gGemm, gGemm+nbA) do bucketA.
// ---------------------------------------------------------------------------
#define ACHUNK 2048
__global__ __launch_bounds__(256) void gemm1_bucketA_kernel(
    const float* __restrict__ A, const unsigned short* __restrict__ BFRAG,
    unsigned short* __restrict__ C, int M, int gGemm,
    const int* __restrict__ src, const int* __restrict__ dst,
    int* __restrict__ bcursor, int2* __restrict__ tmp, int e, int nb) {
    constexpr int NT = 8, KS = 8;
    constexpr int K = KS * 32;                  // 256
    constexpr int LSTRIDE = K + 8;
    __shared__ char smem[64 * LSTRIDE * 2];     // 33792 B (gemm); bucketA uses 9216

    const int tid = threadIdx.x;
    if ((int)blockIdx.x < gGemm) {
        unsigned short* Alds = (unsigned short*)smem;
        const int wave = tid >> 6, lane = tid & 63;
        const int quad = lane >> 4, m16 = lane & 15;
        const int rowBase = blockIdx.x * 64;

        constexpr int HALVES = K / 128;
#pragma unroll
        for (int h = 0; h < HALVES; h++) {
            f32x4 v[8];
#pragma unroll
            for (int it = 0; it < 8; it++) {
                int p = (h * 8 + it) * 1024 + tid * 4;
                int rg = rowBase + p / K;
                if (rg >= M) rg = M - 1;
                v[it] = *(const f32x4*)(A + (size_t)rg * K + (p % K));
            }
#pragma unroll
            for (int it = 0; it < 8; it++) {
                int p = (h * 8 + it) * 1024 + tid * 4;
                BF8 cv;
                cv.h[0] = __float22bfloat162_rn(make_float2(v[it].x, v[it].y));
                cv.h[1] = __float22bfloat162_rn(make_float2(v[it].z, v[it].w));
                *(uint2*)&Alds[(p / K) * LSTRIDE + (p % K)] = make_uint2(cv.u.x, cv.u.y);
            }
        }
        __syncthreads();

        const unsigned short* Afrag0 = &Alds[(wave * 16 + m16) * LSTRIDE + quad * 8];
        const uint4* Bfrag = (const uint4*)BFRAG + lane;

        f32x4 acc[NT];
#pragma unroll
        for (int nt = 0; nt < NT; nt++) acc[nt] = f32x4{0.f, 0.f, 0.f, 0.f};
#pragma unroll
        for (int ks = 0; ks < KS; ks++) {
            BF8 af;
            af.u = *(const uint4*)(Afrag0 + ks * 32);
#pragma unroll
            for (int nt = 0; nt < NT; nt++) {
                BF8 bf;
                bf.u = Bfrag[(nt * KS + ks) * 64];
                acc[nt] = __builtin_amdgcn_mfma_f32_16x16x32_bf16(af.s, bf.s, acc[nt], 0, 0, 0);
            }
        }
        const int rowOut = rowBase + wave * 16 + quad * 4;
#pragma unroll
        for (int nt = 0; nt < NT; nt++) {
#pragma unroll
            for (int r = 0; r < 4; r++) {
                int row = rowOut + r;
                if (row < M)
                    C[(size_t)row * 128 + nt * 16 + m16] = f32_to_bf16_rne(acc[nt][r]);
            }
        }
    } else {
        int* sdst = (int*)smem;               // 2048 ints
        int* hist = (int*)(smem + 8192);      // 256 ints
        const int b0 = blockIdx.x - gGemm;
        const int start = b0 * ACHUNK;
        const int cnt = min(ACHUNK, e - start);
        if (tid < nb) hist[tid] = 0;
        __syncthreads();
        for (int i = tid; i < cnt; i += 256) {
            int d = dst[start + i];
            sdst[i] = d;
            atomicAdd(&hist[d >> 8], 1);
        }
        __syncthreads();
        if (tid < nb) {
            int h = hist[tid];
            hist[tid] = (h > 0) ? atomicAdd(&bcursor[tid], h) : 0;
        }
        __syncthreads();
        for (int i = tid; i < cnt; i += 256) {
            int d = sdst[i];
            int slot = atomicAdd(&hist[d >> 8], 1);
            tmp[slot] = make_int2(src[start + i], d);
        }
    }
}

// ---- bucketB: one block per bucket; finalize CSR records (src, weight) ----
__global__ __launch_bounds__(256) void bucketB_kernel(const int* __restrict__ rowptr,
                                                      const int2* __restrict__ tmp,
                                                      const float* __restrict__ dinv,
                                                      int2* __restrict__ sedge, int n) {
    __shared__ int lcur[256];
    __shared__ float ldinv[256];
    const int tid = threadIdx.x;
    const int nodeBase = blockIdx.x * 256;
    const int nNodes = min(256, n - nodeBase);
    if (tid < nNodes) {
        lcur[tid] = rowptr[nodeBase + tid];
        ldinv[tid] = dinv[nodeBase + tid];
    }
    __syncthreads();
    const int beg = rowptr[nodeBase];
    const int end = rowptr[nodeBase + nNodes];
    for (int i = beg + tid; i < end; i += 256) {
        int2 r = tmp[i];
        int j = r.y - nodeBase;
        float w = dinv[r.x] * ldinv[j];
        int pos = atomicAdd(&lcur[j], 1);
        sedge[pos] = make_int2(r.x, __float_as_int(w));
    }
}

// FOUR nodes per wave (16 lanes each), 128 bf16 ch -> 8 ch/lane (uint4 = full
// 256B row per quarter-wave). Writes a1 = bf16(relu(bias + agg)).
__global__ __launch_bounds__(256) void agg128_kernel(
    const int* __restrict__ rowptr, const int2* __restrict__ sedge,
    const unsigned short* __restrict__ hb, const float* __restrict__ dinv,
    const float* __restrict__ bias, unsigned short* __restrict__ outb, int n) {
    int node = blockIdx.x * 16 + (threadIdx.x >> 4);
    if (node >= n) return;
    int sub = threadIdx.x & 15;
    float di = dinv[node];
    float d2 = di * di;
    uint4 sv = ((const uint4*)(hb + (size_t)node * 128))[sub];
    float a0 = d2 * bf_lo(sv.x), a1 = d2 * bf_hi(sv.x);
    float a2 = d2 * bf_lo(sv.y), a3 = d2 * bf_hi(sv.y);
    float a4 = d2 * bf_lo(sv.z), a5 = d2 * bf_hi(sv.z);
    float a6 = d2 * bf_lo(sv.w), a7 = d2 * bf_hi(sv.w);
    int beg = rowptr[node], end = rowptr[node + 1];
    int i = beg;
    for (; i + 4 <= end; i += 4) {
        int2 e[4];
        uint4 v[4];
#pragma unroll
        for (int j = 0; j < 4; j++) e[j] = sedge[i + j];
#pragma unroll
        for (int j = 0; j < 4; j++)
            v[j] = ((const uint4*)(hb + (size_t)e[j].x * 128))[sub];
#pragma unroll
        for (int j = 0; j < 4; j++) {
            float w = __int_as_float(e[j].y);
            a0 = fmaf(w, bf_lo(v[j].x), a0); a1 = fmaf(w, bf_hi(v[j].x), a1);
            a2 = fmaf(w, bf_lo(v[j].y), a2); a3 = fmaf(w, bf_hi(v[j].y), a3);
            a4 = fmaf(w, bf_lo(v[j].z), a4); a5 = fmaf(w, bf_hi(v[j].z), a5);
            a6 = fmaf(w, bf_lo(v[j].w), a6); a7 = fmaf(w, bf_hi(v[j].w), a7);
        }
    }
    for (; i < end; ++i) {
        int2 e = sedge[i];
        float w = __int_as_float(e.y);
        uint4 v = ((const uint4*)(hb + (size_t)e.x * 128))[sub];
        a0 = fmaf(w, bf_lo(v.x), a0); a1 = fmaf(w, bf_hi(v.x), a1);
        a2 = fmaf(w, bf_lo(v.y), a2); a3 = fmaf(w, bf_hi(v.y), a3);
        a4 = fmaf(w, bf_lo(v.z), a4); a5 = fmaf(w, bf_hi(v.z), a5);
        a6 = fmaf(w, bf_lo(v.w), a6); a7 = fmaf(w, bf_hi(v.w), a7);
    }
    float4 b0 = ((const float4*)bias)[sub * 2];
    float4 b1 = ((const float4*)bias)[sub * 2 + 1];
    BF8 p;
    p.h[0] = __float22bfloat162_rn(make_float2(fmaxf(a0 + b0.x, 0.f), fmaxf(a1 + b0.y, 0.f)));
    p.h[1] = __float22bfloat162_rn(make_float2(fmaxf(a2 + b0.z, 0.f), fmaxf(a3 + b0.w, 0.f)));
    p.h[2] = __float22bfloat162_rn(make_float2(fmaxf(a4 + b1.x, 0.f), fmaxf(a5 + b1.y, 0.f)));
    p.h[3] = __float22bfloat162_rn(make_float2(fmaxf(a6 + b1.z, 0.f), fmaxf(a7 + b1.w, 0.f)));
    ((uint4*)(outb + (size_t)node * 128))[sub] = p.u;
}

// FOUR nodes per wave, 64 bf16 ch -> 4 ch/lane (uint2). Writes f32 out+bias.
__global__ __launch_bounds__(256) void agg64_kernel(
    const int* __restrict__ rowptr, const int2* __restrict__ sedge,
    const unsigned short* __restrict__ hb, const float* __restrict__ dinv,
    const float* __restrict__ bias, float* __restrict__ out, int n) {
    int node = blockIdx.x * 16 + (threadIdx.x >> 4);
    if (node >= n) return;
    int sub = threadIdx.x & 15;
    float di = dinv[node];
    float d2 = di * di;
    uint2 sv = ((const uint2*)(hb + (size_t)node * 64))[sub];
    float a0 = d2 * bf_lo(sv.x), a1 = d2 * bf_hi(sv.x);
    float a2 = d2 * bf_lo(sv.y), a3 = d2 * bf_hi(sv.y);
    int beg = rowptr[node], end = rowptr[node + 1];
    int i = beg;
    for (; i + 8 <= end; i += 8) {
        int2 e[8];
        uint2 v[8];
#pragma unroll
        for (int j = 0; j < 8; j++) e[j] = sedge[i + j];
#pragma unroll
        for (int j = 0; j < 8; j++)
            v[j] = ((const uint2*)(hb + (size_t)e[j].x * 64))[sub];
#pragma unroll
        for (int j = 0; j < 8; j++) {
            float w = __int_as_float(e[j].y);
            a0 = fmaf(w, bf_lo(v[j].x), a0); a1 = fmaf(w, bf_hi(v[j].x), a1);
            a2 = fmaf(w, bf_lo(v[j].y), a2); a3 = fmaf(w, bf_hi(v[j].y), a3);
        }
    }
    for (; i + 4 <= end; i += 4) {
        int2 e[4];
        uint2 v[4];
#pragma unroll
        for (int j = 0; j < 4; j++) e[j] = sedge[i + j];
#pragma unroll
        for (int j = 0; j < 4; j++)
            v[j] = ((const uint2*)(hb + (size_t)e[j].x * 64))[sub];
#pragma unroll
        for (int j = 0; j < 4; j++) {
            float w = __int_as_float(e[j].y);
            a0 = fmaf(w, bf_lo(v[j].x), a0); a1 = fmaf(w, bf_hi(v[j].x), a1);
            a2 = fmaf(w, bf_lo(v[j].y), a2); a3 = fmaf(w, bf_hi(v[j].y), a3);
        }
    }
    for (; i < end; ++i) {
        int2 e = sedge[i];
        float w = __int_as_float(e.y);
        uint2 v = ((const uint2*)(hb + (size_t)e.x * 64))[sub];
        a0 = fmaf(w, bf_lo(v.x), a0); a1 = fmaf(w, bf_hi(v.x), a1);
        a2 = fmaf(w, bf_lo(v.y), a2); a3 = fmaf(w, bf_hi(v.y), a3);
    }
    float4 bv = ((const float4*)bias)[sub];
    ((float4*)(out + (size_t)node * 64))[sub] =
        make_float4(a0 + bv.x, a1 + bv.y, a2 + bv.z, a3 + bv.w);
}

// ---------------------------------------------------------------------------
// MFMA bf16 GEMM (layer 2): bf16 A, fragment-linear B.
// ---------------------------------------------------------------------------
template <int NT, int KS>
__global__ __launch_bounds__(256) void mfma_gemm_bfA_kernel(
    const unsigned short* __restrict__ A, const unsigned short* __restrict__ BFRAG,
    unsigned short* __restrict__ C, int M) {
    constexpr int NCOL = NT * 16;
    constexpr int K = KS * 32;
    constexpr int LSTRIDE = K + 8;
    __shared__ unsigned short Alds[64 * LSTRIDE];

    const int tid = threadIdx.x;
    const int wave = tid >> 6, lane = tid & 63;
    const int quad = lane >> 4, m16 = lane & 15;
    const int rowBase = blockIdx.x * 64;

    constexpr int ITERS = K / 32;
    uint4 v[ITERS];
#pragma unroll
    for (int it = 0; it < ITERS; it++) {
        int p = it * 2048 + tid * 8;
        int rg = rowBase + p / K;
        if (rg >= M) rg = M - 1;
        v[it] = *(const uint4*)(A + (size_t)rg * K + (p % K));
    }
#pragma unroll
    for (int it = 0; it < ITERS; it++) {
        int p = it * 2048 + tid * 8;
        *(uint4*)&Alds[(p / K) * LSTRIDE + (p % K)] = v[it];
    }
    __syncthreads();

    const unsigned short* Afrag0 = &Alds[(wave * 16 + m16) * LSTRIDE + quad * 8];
    const uint4* Bfrag = (const uint4*)BFRAG + lane;

    f32x4 acc[NT];
#pragma unroll
    for (int nt = 0; nt < NT; nt++) acc[nt] = f32x4{0.f, 0.f, 0.f, 0.f};
#pragma unroll
    for (int ks = 0; ks < KS; ks++) {
        BF8 af;
        af.u = *(const uint4*)(Afrag0 + ks * 32);
#pragma unroll
        for (int nt = 0; nt < NT; nt++) {
            BF8 bf;
            bf.u = Bfrag[(nt * KS + ks) * 64];
            acc[nt] = __builtin_amdgcn_mfma_f32_16x16x32_bf16(af.s, bf.s, acc[nt], 0, 0, 0);
        }
    }
    const int rowOut = rowBase + wave * 16 + quad * 4;
#pragma unroll
    for (int nt = 0; nt < NT; nt++) {
#pragma unroll
        for (int r = 0; r < 4; r++) {
            int row = rowOut + r;
            if (row < M)
                C[(size_t)row * NCOL + nt * 16 + m16] = f32_to_bf16_rne(acc[nt][r]);
        }
    }
}

extern "C" void kernel_launch(void* const* d_in, const int* in_sizes, int n_in,
                              void* d_out, int out_size, void* d_ws, size_t ws_size,
                              hipStream_t stream) {
    const float* x  = (const float*)d_in[0];
    const int*   ei = (const int*)d_in[1];   // [2, E] flat: src row then dst row
    const float* W1 = (const float*)d_in[2];
    const float* b1 = (const float*)d_in[3];
    const float* W2 = (const float*)d_in[4];
    const float* b2 = (const float*)d_in[5];
    float* out = (float*)d_out;

    const int IN_C = 256;
    const int N = in_sizes[0] / IN_C;
    const int E = in_sizes[1] / 2;
    const int* srcA = ei;
    const int* dstA = ei + E;

    char* ws = (char*)d_ws;
    const size_t KB = 1024, MB = 1024 * 1024;
    int*            counts  = (int*)(ws);                    // N ints
    float*          dinv    = (float*)(ws + 256 * KB);       // N floats
    int*            rowptr  = (int*)(ws + 512 * KB);         // N+1 ints
    int*            bcursor = (int*)(ws + 768 * KB);         // <=256 ints
    int*            bflag   = (int*)(ws + 960 * KB);         // 64 ints
    int*            bsum    = (int*)(ws + 992 * KB);         // 64 ints
    unsigned short* w1f     = (unsigned short*)(ws + 1 * MB);           // 32768 bf16
    unsigned short* w2f     = (unsigned short*)(ws + 1 * MB + 64 * KB); // 8192 bf16
    int2*           sedge   = (int2*)(ws + 2 * MB);          // E int2 (6.4 MB)
    int2*           tmp     = (int2*)(ws + 9 * MB);          // E int2 (6.4 MB)
    unsigned short* h1b     = (unsigned short*)(ws + 16 * MB); // N*128 bf16
    unsigned short* a1b     = (unsigned short*)(ws + 29 * MB); // N*128 bf16
    unsigned short* h2b     = h1b;                           // reuse (N*64 bf16)

    const int eb256 = (E + 255) / 256;
    const int nbScan = (N + 1 + 1023) / 1024;  // <=64 (N<=65536)
    const int NB = (N + 255) / 256;            // coarse buckets (<=256)
    const int gGemm = (N + 63) / 64;
    const int nbA = (E + ACHUNK - 1) / ACHUNK;
    const int gWfrag = (max(N, 32768 + 8192) + 255) / 256;

    // 1: weights fragment-repack + zero counts/bflag
    wfrag_zero_kernel<<<gWfrag, 256, 0, stream>>>(W1, W2, w1f, w2f, counts, bflag, N);
    // 2: degree count
    count_deg_kernel<<<eb256, 256, 0, stream>>>(dstA, counts, E);
    // 3: fused scan (decoupled lookback) -> rowptr, bcursor, dinv
    scan_fused_kernel<<<nbScan, 256, 0, stream>>>(counts, dinv, rowptr, bcursor, bsum, bflag, N);
    // 4: gemm1 + bucketA fused
    gemm1_bucketA_kernel<<<gGemm + nbA, 256, 0, stream>>>(
        x, w1f, h1b, N, gGemm, srcA, dstA, bcursor, tmp, E, NB);
    // 5: bucketB -> sedge
    bucketB_kernel<<<NB, 256, 0, stream>>>(rowptr, tmp, dinv, sedge, N);
    // 6: agg layer 1 -> a1 (bf16, relu+bias fused)
    agg128_kernel<<<(N + 15) / 16, 256, 0, stream>>>(rowptr, sedge, h1b, dinv, b1, a1b, N);
    // 7: gemm2
    mfma_gemm_bfA_kernel<4, 4><<<gGemm, 256, 0, stream>>>(a1b, w2f, h2b, N);
    // 8: agg layer 2 -> out (f32)
    agg64_kernel<<<(N + 15) / 16, 256, 0, stream>>>(rowptr, sedge, h2b, dinv, b2, out, N);
}